// Round 1
// baseline (271.086 us; speedup 1.0000x reference)
//
#include <hip/hip_runtime.h>
#include <math.h>

#define NB 128
#define NS 300   // pred slots
#define NG 100   // gt slots
#define NP 10    // params per stroke

// ---------------------------------------------------------------------------
// One block (= one wave of 64 lanes) per batch element.
// Phase 1: stage strokes/probs/valid-targets in LDS.
// Phase 2: Jonker-Volgenant LAP (n = nv rows = valid targets, m = 300 cols =
//          pred slots; this is the reference's "transposed" branch since
//          nv <= 100 < 300). Cost entries recomputed on the fly in f64 from
//          f32 staged inputs -> bitwise-equivalent to numpy's f64 cost matrix
//          (modulo expf-vs-XLA-exp ~1ulp in the f32 softmax, matching the
//          reference's own f32 softmax rounding).
// Phase 3: fused loss partials (matched L1/SmoothL1/width + weighted CE over
//          all 300 slots), f64 atomicAdd into global accumulators.
// ---------------------------------------------------------------------------

__device__ __forceinline__ double wave_sum(double v) {
  #pragma unroll
  for (int off = 32; off > 0; off >>= 1) v += __shfl_xor(v, off);
  return v;
}

__global__ __launch_bounds__(64) void detr_match_loss_kernel(
    const float* __restrict__ strokes,   // [B,300,10]
    const float* __restrict__ logits,    // [B,300,3]
    const float* __restrict__ tparams,   // [B,100,10]
    const int*   __restrict__ tlabels,   // [B,100]
    double*      __restrict__ acc)       // [6]: wnll, wsum, l1, sl1, width, count
{
  __shared__ float  s_strokes[NS * NP];   // 12000 B
  __shared__ float  s_probs[NS * 3];      //  3600 B
  __shared__ float  s_vt[NG * NP];        //  4000 B
  __shared__ int    s_valid[NG];
  __shared__ int    s_vlab[NG];
  __shared__ double s_u[NG];
  __shared__ int    s_col4row[NG];
  __shared__ int    s_SRb[NG];
  __shared__ double s_shortest[NS];
  __shared__ double s_v[NS];
  __shared__ int    s_path[NS];
  __shared__ int    s_SC[NS];
  __shared__ int    s_row4col[NS];
  __shared__ int    s_tc[NS];
  __shared__ int    s_nv;

  const int b    = blockIdx.x;
  const int lane = threadIdx.x;

  // ---- stage strokes (coalesced) ----
  for (int idx = lane; idx < NS * NP; idx += 64)
    s_strokes[idx] = strokes[b * NS * NP + idx];

  // ---- f32 softmax (matches jax.nn.softmax rounding) + per-col init ----
  for (int j = lane; j < NS; j += 64) {
    const float x0 = logits[(b * NS + j) * 3 + 0];
    const float x1 = logits[(b * NS + j) * 3 + 1];
    const float x2 = logits[(b * NS + j) * 3 + 2];
    const float m  = fmaxf(x0, fmaxf(x1, x2));
    const float e0 = expf(x0 - m), e1 = expf(x1 - m), e2 = expf(x2 - m);
    const float s  = e0 + e1 + e2;
    s_probs[j * 3 + 0] = e0 / s;
    s_probs[j * 3 + 1] = e1 / s;
    s_probs[j * 3 + 2] = e2 / s;
    s_tc[j]      = 0;
    s_row4col[j] = -1;
    s_v[j]       = 0.0;
  }

  // ---- build valid-target list (serial scan, order matters) ----
  if (lane == 0) {
    int nv = 0;
    for (int g = 0; g < NG; ++g) {
      const int lb = tlabels[b * NG + g];
      if (lb > 0) { s_valid[nv] = g; s_vlab[nv] = lb; ++nv; }
    }
    s_nv = nv;
  }
  __syncthreads();
  const int nv = s_nv;

  for (int idx = lane; idx < nv * NP; idx += 64) {
    const int i = idx / NP, k = idx % NP;
    s_vt[idx] = tparams[(b * NG + s_valid[i]) * NP + k];
  }
  for (int i = lane; i < nv; i += 64) { s_u[i] = 0.0; s_col4row[i] = -1; }
  __syncthreads();

  if (nv > 0) {
    for (int cur = 0; cur < nv; ++cur) {
      // reset per-augmentation state
      for (int j = lane; j < NS; j += 64) {
        s_shortest[j] = 1e300;
        s_path[j]     = -1;
        s_SC[j]       = 0;
      }
      for (int r = lane; r < nv; r += 64) s_SRb[r] = 0;
      __syncthreads();

      double minVal = 0.0;
      int i = cur;
      int sink = -1;

      while (sink == -1) {
        if (lane == 0) s_SRb[i] = 1;

        // uniform row-i data (LDS broadcast reads)
        const double ui  = s_u[i];
        const int    cls = s_vlab[i];
        double vtr[NP];
        #pragma unroll
        for (int k = 0; k < NP; ++k) vtr[k] = (double)s_vt[i * NP + k];
        const double base = minVal - ui;

        double bestv = 1e300;
        int    bestj = 0x7fffffff;

        for (int j = lane; j < NS; j += 64) {
          if (!s_SC[j]) {
            const double p = (double)s_probs[j * 3 + cls];
            double a[NP];
            #pragma unroll
            for (int k = 0; k < NP; ++k)
              a[k] = fabs((double)s_strokes[j * NP + k] - vtr[k]);
            const double coord = ((a[0] + a[1]) + (a[2] + a[3])) +
                                 ((a[4] + a[5]) + (a[6] + a[7]));
            const double c = -p + 5.0 * coord + 2.0 * (a[8] + a[9]) +
                             2.0 * (a[0] + a[1]);
            const double d = base + c - s_v[j];
            if (d < s_shortest[j]) { s_shortest[j] = d; s_path[j] = i; }
            const double sv = s_shortest[j];
            if (sv < bestv) { bestv = sv; bestj = j; }
          }
        }

        // wave argmin, low-index tie-break (matches np.argmin)
        #pragma unroll
        for (int off = 32; off > 0; off >>= 1) {
          const double ov = __shfl_xor(bestv, off);
          const int    oj = __shfl_xor(bestj, off);
          if (ov < bestv || (ov == bestv && oj < bestj)) { bestv = ov; bestj = oj; }
        }
        minVal = bestv;
        const int jstar = bestj;
        if (lane == 0) s_SC[jstar] = 1;
        __syncthreads();
        const int rc = s_row4col[jstar];
        if (rc < 0) sink = jstar; else i = rc;
      }

      // dual updates (pre-augmentation col4row, as in reference)
      for (int r = lane; r < nv; r += 64)
        if (s_SRb[r] && r != cur)
          s_u[r] += minVal - s_shortest[s_col4row[r]];
      if (lane == 0) s_u[cur] += minVal;
      for (int j = lane; j < NS; j += 64)
        if (s_SC[j]) s_v[j] -= minVal - s_shortest[j];
      __syncthreads();

      // augmenting-path flip (serial, lane 0)
      if (lane == 0) {
        int j = sink;
        while (true) {
          const int i2 = s_path[j];
          s_row4col[j] = i2;
          const int nxt = s_col4row[i2];
          s_col4row[i2] = j;
          if (i2 == cur) break;
          j = nxt;
        }
      }
      __syncthreads();
    }

    // ---- matched regression partials + tc scatter ----
    double l1 = 0.0, sl1 = 0.0, wid = 0.0;
    for (int i = lane; i < nv; i += 64) {
      const int r = s_col4row[i];
      s_tc[r] = s_vlab[i];
      #pragma unroll
      for (int k = 0; k < 8; ++k) {
        const float d  = s_strokes[r * NP + k] - s_vt[i * NP + k];
        const float ad = fabsf(d);
        l1 += (double)ad;
        const float s = (ad < 0.1f) ? (0.5f * ad * ad / 0.1f) : (ad - 0.05f);
        sl1 += (double)s;
      }
      const float d8 = fabsf(s_strokes[r * NP + 8] - s_vt[i * NP + 8]);
      const float d9 = fabsf(s_strokes[r * NP + 9] - s_vt[i * NP + 9]);
      wid += (double)d8 + (double)d9;
    }
    l1 = wave_sum(l1); sl1 = wave_sum(sl1); wid = wave_sum(wid);
    if (lane == 0) {
      atomicAdd(&acc[2], l1);
      atomicAdd(&acc[3], sl1);
      atomicAdd(&acc[4], wid);
      atomicAdd(&acc[5], (double)nv);
    }
  }
  __syncthreads();

  // ---- weighted CE over all 300 slots (runs even when nv == 0) ----
  double wnll = 0.0, wsum = 0.0;
  for (int s = lane; s < NS; s += 64) {
    const int tc = s_tc[s];
    const double x0 = (double)logits[(b * NS + s) * 3 + 0];
    const double x1 = (double)logits[(b * NS + s) * 3 + 1];
    const double x2 = (double)logits[(b * NS + s) * 3 + 2];
    const double m   = fmax(x0, fmax(x1, x2));
    const double lse = log(exp(x0 - m) + exp(x1 - m) + exp(x2 - m));
    const double xt  = (tc == 0) ? x0 : ((tc == 1) ? x1 : x2);
    const double nll = -(xt - m - lse);
    const double w   = (tc == 0) ? 0.1 : 1.0;
    wnll += w * nll;
    wsum += w;
  }
  wnll = wave_sum(wnll); wsum = wave_sum(wsum);
  if (lane == 0) {
    atomicAdd(&acc[0], wnll);
    atomicAdd(&acc[1], wsum);
  }
}

__global__ void detr_finalize_kernel(const double* __restrict__ acc,
                                     float* __restrict__ out) {
  const double loss_ce = acc[0] / acc[1];
  const double denom   = fmax(acc[5], 1.0);
  const double loss = 1.0 * loss_ce                      // CLASS_W
                    + 5.0 * (acc[2] + acc[3]) / denom    // COORD_W * (l1+sl1)/denom
                    + 2.0 * acc[4] / denom;              // WIDTH_W
  out[0] = (float)loss;
}

extern "C" void kernel_launch(void* const* d_in, const int* in_sizes, int n_in,
                              void* d_out, int out_size, void* d_ws, size_t ws_size,
                              hipStream_t stream) {
  const float* strokes = (const float*)d_in[0];
  const float* logits  = (const float*)d_in[1];
  const float* tparams = (const float*)d_in[2];
  const int*   tlabels = (const int*)d_in[3];
  double* acc = (double*)d_ws;

  hipMemsetAsync(d_ws, 0, 6 * sizeof(double), stream);
  detr_match_loss_kernel<<<NB, 64, 0, stream>>>(strokes, logits, tparams,
                                                tlabels, acc);
  detr_finalize_kernel<<<1, 1, 0, stream>>>(acc, (float*)d_out);
}

// Round 2
// 214.790 us; speedup vs baseline: 1.2621x; 1.2621x over previous
//
#include <hip/hip_runtime.h>
#include <math.h>

#define NB 128
#define NS 300   // pred slots (columns)
#define NG 100   // gt slots (max rows)
#define NP 10    // params per stroke
#define NSLOT 5  // ceil(NS/64)

// ws layout: [0,64): acc doubles; [1024, 1024+128*100*300*8): cost matrix C
#define WS_C_OFF 1024
#define WS_NEEDED (WS_C_OFF + (size_t)NB * NG * NS * 8)

#define GET_SLOT(arr, slot, out) do { switch (slot) { \
  case 0: out = arr[0]; break; case 1: out = arr[1]; break; \
  case 2: out = arr[2]; break; case 3: out = arr[3]; break; \
  default: out = arr[4]; break; } } while (0)
#define SET_SLOT(arr, slot, val) do { switch (slot) { \
  case 0: arr[0] = val; break; case 1: arr[1] = val; break; \
  case 2: arr[2] = val; break; case 3: arr[3] = val; break; \
  default: arr[4] = val; break; } } while (0)

__device__ __forceinline__ double wave_sum(double v) {
  #pragma unroll
  for (int off = 32; off > 0; off >>= 1) v += __shfl_xor(v, off);
  return v;
}

// ---------------------------------------------------------------------------
// Kernel B: precompute f64 cost matrix C[b][i][j] for valid rows i < nv.
// Bitwise-identical to the reference's numpy f64 cost (same f32 softmax, exact
// f32->f64 subtraction, same pairwise-sum grouping).
// ---------------------------------------------------------------------------
__global__ __launch_bounds__(256) void detr_cost_kernel(
    const float* __restrict__ strokes,   // [B,300,10]
    const float* __restrict__ logits,    // [B,300,3]
    const float* __restrict__ tparams,   // [B,100,10]
    const int*   __restrict__ tlabels,   // [B,100]
    double*      __restrict__ C)         // [B,100,300]
{
  __shared__ float sS[NS * NP];   // strokes
  __shared__ float sP[NS * 3];    // probs
  __shared__ float sVT[10 * NP];  // this chunk's target params
  __shared__ int   sCls[10];
  __shared__ int   s_valid[NG];
  __shared__ int   s_vlab[NG];
  __shared__ int   s_nv;

  const int b   = blockIdx.x;
  const int cb  = blockIdx.y;    // row chunk: rows [cb*10, cb*10+10)
  const int tid = threadIdx.x;

  for (int idx = tid; idx < NS * NP; idx += 256)
    sS[idx] = strokes[b * NS * NP + idx];

  for (int j = tid; j < NS; j += 256) {
    const float x0 = logits[(b * NS + j) * 3 + 0];
    const float x1 = logits[(b * NS + j) * 3 + 1];
    const float x2 = logits[(b * NS + j) * 3 + 2];
    const float m  = fmaxf(x0, fmaxf(x1, x2));
    const float e0 = expf(x0 - m), e1 = expf(x1 - m), e2 = expf(x2 - m);
    const float s  = e0 + e1 + e2;
    sP[j * 3 + 0] = e0 / s;
    sP[j * 3 + 1] = e1 / s;
    sP[j * 3 + 2] = e2 / s;
  }

  // stable compaction of valid targets via wave-0 ballots
  if (tid < 64) {
    const unsigned long long below = (1ull << tid) - 1ull;
    const int lb1 = tlabels[b * NG + tid];                    // g = tid (0..63)
    const bool in2 = tid < (NG - 64);                         // g = 64+tid
    const int lb2 = in2 ? tlabels[b * NG + 64 + tid] : 0;
    const unsigned long long m1 = __ballot(lb1 > 0);
    const unsigned long long m2 = __ballot(in2 && lb2 > 0);
    const int c1 = __popcll(m1);
    if (lb1 > 0) {
      const int p = __popcll(m1 & below);
      s_valid[p] = tid; s_vlab[p] = lb1;
    }
    if (in2 && lb2 > 0) {
      const int p = c1 + __popcll(m2 & below);
      s_valid[p] = 64 + tid; s_vlab[p] = lb2;
    }
    if (tid == 0) s_nv = c1 + __popcll(m2);
  }
  __syncthreads();

  const int nv = s_nv;
  const int i0 = cb * 10;
  const int nrow = (nv - i0 < 10) ? (nv - i0) : 10;
  if (nrow <= 0) return;

  for (int idx = tid; idx < nrow * NP; idx += 256) {
    const int il = idx / NP, k = idx % NP;
    sVT[il * NP + k] = tparams[(b * NG + s_valid[i0 + il]) * NP + k];
  }
  if (tid < nrow) sCls[tid] = s_vlab[i0 + tid];
  __syncthreads();

  for (int e = tid; e < nrow * NS; e += 256) {
    const int il = e / NS, j = e - il * NS;
    const int cls = sCls[il];
    const double p = (double)sP[j * 3 + cls];
    double a[NP];
    #pragma unroll
    for (int k = 0; k < NP; ++k)
      a[k] = fabs((double)sS[j * NP + k] - (double)sVT[il * NP + k]);
    const double coord = ((a[0] + a[1]) + (a[2] + a[3])) +
                         ((a[4] + a[5]) + (a[6] + a[7]));
    const double c = -p + 5.0 * coord + 2.0 * (a[8] + a[9]) +
                     2.0 * (a[0] + a[1]);
    C[((size_t)b * NG + (i0 + il)) * NS + j] = c;
  }
}

// ---------------------------------------------------------------------------
// Kernel C: JV LAP with register-resident column state + fused loss.
// One wave per batch; inner Dijkstra loop is barrier-free and LDS-light.
// ---------------------------------------------------------------------------
__global__ __launch_bounds__(64) void detr_match_fast_kernel(
    const float* __restrict__ strokes,
    const float* __restrict__ logits,
    const float* __restrict__ tparams,
    const int*   __restrict__ tlabels,
    const double* __restrict__ C,
    double*      __restrict__ acc)       // [6]: wnll, wsum, l1, sl1, width, count
{
  __shared__ float  s_strokes[NS * NP];
  __shared__ float  s_vt[NG * NP];
  __shared__ int    s_valid[NG];
  __shared__ int    s_vlab[NG];
  __shared__ double s_u[NG];
  __shared__ int    s_col4row[NG];
  __shared__ int    s_SR[NG + 4];
  __shared__ double s_short[NS];
  __shared__ int    s_tc[NS];

  const int b    = blockIdx.x;
  const int lane = threadIdx.x;

  for (int idx = lane; idx < NS * NP; idx += 64)
    s_strokes[idx] = strokes[b * NS * NP + idx];
  for (int j = lane; j < NS; j += 64) s_tc[j] = 0;

  // stable compaction via ballots (order = ascending g, matches np.where)
  const unsigned long long below = (1ull << lane) - 1ull;
  const int lb1 = tlabels[b * NG + lane];
  const bool in2 = lane < (NG - 64);
  const int lb2 = in2 ? tlabels[b * NG + 64 + lane] : 0;
  const unsigned long long m1 = __ballot(lb1 > 0);
  const unsigned long long m2 = __ballot(in2 && lb2 > 0);
  const int c1 = __popcll(m1);
  if (lb1 > 0) {
    const int p = __popcll(m1 & below);
    s_valid[p] = lane; s_vlab[p] = lb1;
  }
  if (in2 && lb2 > 0) {
    const int p = c1 + __popcll(m2 & below);
    s_valid[p] = 64 + lane; s_vlab[p] = lb2;
  }
  const int nv = c1 + __popcll(m2);
  __syncthreads();

  for (int idx = lane; idx < nv * NP; idx += 64) {
    const int i = idx / NP, k = idx % NP;
    s_vt[idx] = tparams[(b * NG + s_valid[i]) * NP + k];
  }
  for (int i = lane; i < nv; i += 64) { s_u[i] = 0.0; s_col4row[i] = -1; }
  __syncthreads();

  if (nv > 0) {
    const double* Cb = C + (size_t)b * NG * NS;
    const double INF = (double)INFINITY;

    // register-resident column state: j = lane + 64*s
    double vv[NSLOT];
    int    r4c[NSLOT];
    #pragma unroll
    for (int s = 0; s < NSLOT; ++s) { vv[s] = 0.0; r4c[s] = -1; }
    const int vmask = (lane < NS - 4 * 64) ? 0x1F : 0x0F;  // NS-256 = 44

    for (int cur = 0; cur < nv; ++cur) {
      double sh[NSLOT];
      int    pa[NSLOT];
      #pragma unroll
      for (int s = 0; s < NSLOT; ++s) { sh[s] = INF; pa[s] = -1; }
      int scm = 0;          // SC bitmask over this lane's slots
      int srn = 0;          // SR count (uniform)
      double minVal = 0.0;
      int i = cur;
      int sink = -1;

      while (sink == -1) {
        if (lane == 0) s_SR[srn] = i;
        srn++;
        const double base = minVal - s_u[i];     // broadcast LDS read
        const double* Crow = Cb + (size_t)i * NS;

        double bestv = INF;
        int    bestj = 0x7fffffff;
        #pragma unroll
        for (int s = 0; s < NSLOT; ++s) {
          if ((vmask >> s) & 1) {
            const double c = Crow[lane + 64 * s];
            if (!((scm >> s) & 1)) {
              const double d = base + c - vv[s];
              if (d < sh[s]) { sh[s] = d; pa[s] = i; }
              if (sh[s] < bestv) { bestv = sh[s]; bestj = lane + 64 * s; }
            }
          }
        }

        // lexicographic wave argmin (value, then lowest j) = np.argmin
        #pragma unroll
        for (int off = 32; off > 0; off >>= 1) {
          const double ov = __shfl_xor(bestv, off);
          const int    oj = __shfl_xor(bestj, off);
          if (ov < bestv || (ov == bestv && oj < bestj)) { bestv = ov; bestj = oj; }
        }
        minVal = bestv;
        const int jstar = bestj;
        const int src  = jstar & 63;
        const int slot = jstar >> 6;     // uniform
        if (lane == src) scm |= (1 << slot);

        int t;
        GET_SLOT(r4c, slot, t);
        const int rc = __shfl(t, src);
        if (rc < 0) sink = jstar; else i = rc;
      }

      // expose shortest to LDS for the dual update
      #pragma unroll
      for (int s = 0; s < NSLOT; ++s)
        if ((vmask >> s) & 1) s_short[lane + 64 * s] = sh[s];
      __syncthreads();

      for (int t2 = lane; t2 < srn; t2 += 64) {
        const int r = s_SR[t2];
        if (r != cur) s_u[r] += minVal - s_short[s_col4row[r]];
      }
      if (lane == 0) s_u[cur] += minVal;
      #pragma unroll
      for (int s = 0; s < NSLOT; ++s)
        if ((scm >> s) & 1) vv[s] -= minVal - sh[s];
      __syncthreads();

      // augmenting-path flip (uniform walk; register gathers via shuffles)
      int j = sink;
      while (true) {
        const int slot = j >> 6, src = j & 63;
        int t;
        GET_SLOT(pa, slot, t);
        const int i2 = __shfl(t, src);
        if (lane == src) SET_SLOT(r4c, slot, i2);
        const int nxt = s_col4row[i2];
        if (lane == 0) s_col4row[i2] = j;
        if (i2 == cur) break;
        j = nxt;
      }
      __syncthreads();
    }

    // matched regression partials + tc scatter
    double l1 = 0.0, sl1 = 0.0, wid = 0.0;
    for (int i = lane; i < nv; i += 64) {
      const int r = s_col4row[i];
      s_tc[r] = s_vlab[i];
      #pragma unroll
      for (int k = 0; k < 8; ++k) {
        const float d  = s_strokes[r * NP + k] - s_vt[i * NP + k];
        const float ad = fabsf(d);
        l1 += (double)ad;
        const float sm = (ad < 0.1f) ? (0.5f * ad * ad / 0.1f) : (ad - 0.05f);
        sl1 += (double)sm;
      }
      const float d8 = fabsf(s_strokes[r * NP + 8] - s_vt[i * NP + 8]);
      const float d9 = fabsf(s_strokes[r * NP + 9] - s_vt[i * NP + 9]);
      wid += (double)d8 + (double)d9;
    }
    l1 = wave_sum(l1); sl1 = wave_sum(sl1); wid = wave_sum(wid);
    if (lane == 0) {
      atomicAdd(&acc[2], l1);
      atomicAdd(&acc[3], sl1);
      atomicAdd(&acc[4], wid);
      atomicAdd(&acc[5], (double)nv);
    }
  }
  __syncthreads();

  // weighted CE over all 300 slots
  double wnll = 0.0, wsum = 0.0;
  for (int s = lane; s < NS; s += 64) {
    const int tc = s_tc[s];
    const double x0 = (double)logits[(b * NS + s) * 3 + 0];
    const double x1 = (double)logits[(b * NS + s) * 3 + 1];
    const double x2 = (double)logits[(b * NS + s) * 3 + 2];
    const double m   = fmax(x0, fmax(x1, x2));
    const double lse = log(exp(x0 - m) + exp(x1 - m) + exp(x2 - m));
    const double xt  = (tc == 0) ? x0 : ((tc == 1) ? x1 : x2);
    const double nll = -(xt - m - lse);
    const double w   = (tc == 0) ? 0.1 : 1.0;
    wnll += w * nll;
    wsum += w;
  }
  wnll = wave_sum(wnll); wsum = wave_sum(wsum);
  if (lane == 0) {
    atomicAdd(&acc[0], wnll);
    atomicAdd(&acc[1], wsum);
  }
}

// ---------------------------------------------------------------------------
// Fallback: round-0 monolithic kernel (used only if ws_size is too small).
// ---------------------------------------------------------------------------
__global__ __launch_bounds__(64) void detr_match_loss_kernel(
    const float* __restrict__ strokes,
    const float* __restrict__ logits,
    const float* __restrict__ tparams,
    const int*   __restrict__ tlabels,
    double*      __restrict__ acc)
{
  __shared__ float  s_strokes[NS * NP];
  __shared__ float  s_probs[NS * 3];
  __shared__ float  s_vt[NG * NP];
  __shared__ int    s_valid[NG];
  __shared__ int    s_vlab[NG];
  __shared__ double s_u[NG];
  __shared__ int    s_col4row[NG];
  __shared__ int    s_SRb[NG];
  __shared__ double s_shortest[NS];
  __shared__ double s_v[NS];
  __shared__ int    s_path[NS];
  __shared__ int    s_SC[NS];
  __shared__ int    s_row4col[NS];
  __shared__ int    s_tc[NS];
  __shared__ int    s_nv;

  const int b    = blockIdx.x;
  const int lane = threadIdx.x;

  for (int idx = lane; idx < NS * NP; idx += 64)
    s_strokes[idx] = strokes[b * NS * NP + idx];

  for (int j = lane; j < NS; j += 64) {
    const float x0 = logits[(b * NS + j) * 3 + 0];
    const float x1 = logits[(b * NS + j) * 3 + 1];
    const float x2 = logits[(b * NS + j) * 3 + 2];
    const float m  = fmaxf(x0, fmaxf(x1, x2));
    const float e0 = expf(x0 - m), e1 = expf(x1 - m), e2 = expf(x2 - m);
    const float s  = e0 + e1 + e2;
    s_probs[j * 3 + 0] = e0 / s;
    s_probs[j * 3 + 1] = e1 / s;
    s_probs[j * 3 + 2] = e2 / s;
    s_tc[j]      = 0;
    s_row4col[j] = -1;
    s_v[j]       = 0.0;
  }

  if (lane == 0) {
    int nv = 0;
    for (int g = 0; g < NG; ++g) {
      const int lb = tlabels[b * NG + g];
      if (lb > 0) { s_valid[nv] = g; s_vlab[nv] = lb; ++nv; }
    }
    s_nv = nv;
  }
  __syncthreads();
  const int nv = s_nv;

  for (int idx = lane; idx < nv * NP; idx += 64) {
    const int i = idx / NP, k = idx % NP;
    s_vt[idx] = tparams[(b * NG + s_valid[i]) * NP + k];
  }
  for (int i = lane; i < nv; i += 64) { s_u[i] = 0.0; s_col4row[i] = -1; }
  __syncthreads();

  if (nv > 0) {
    for (int cur = 0; cur < nv; ++cur) {
      for (int j = lane; j < NS; j += 64) {
        s_shortest[j] = 1e300;
        s_path[j]     = -1;
        s_SC[j]       = 0;
      }
      for (int r = lane; r < nv; r += 64) s_SRb[r] = 0;
      __syncthreads();

      double minVal = 0.0;
      int i = cur;
      int sink = -1;

      while (sink == -1) {
        if (lane == 0) s_SRb[i] = 1;
        const double ui  = s_u[i];
        const int    cls = s_vlab[i];
        double vtr[NP];
        #pragma unroll
        for (int k = 0; k < NP; ++k) vtr[k] = (double)s_vt[i * NP + k];
        const double base = minVal - ui;

        double bestv = 1e300;
        int    bestj = 0x7fffffff;

        for (int j = lane; j < NS; j += 64) {
          if (!s_SC[j]) {
            const double p = (double)s_probs[j * 3 + cls];
            double a[NP];
            #pragma unroll
            for (int k = 0; k < NP; ++k)
              a[k] = fabs((double)s_strokes[j * NP + k] - vtr[k]);
            const double coord = ((a[0] + a[1]) + (a[2] + a[3])) +
                                 ((a[4] + a[5]) + (a[6] + a[7]));
            const double c = -p + 5.0 * coord + 2.0 * (a[8] + a[9]) +
                             2.0 * (a[0] + a[1]);
            const double d = base + c - s_v[j];
            if (d < s_shortest[j]) { s_shortest[j] = d; s_path[j] = i; }
            const double sv = s_shortest[j];
            if (sv < bestv) { bestv = sv; bestj = j; }
          }
        }

        #pragma unroll
        for (int off = 32; off > 0; off >>= 1) {
          const double ov = __shfl_xor(bestv, off);
          const int    oj = __shfl_xor(bestj, off);
          if (ov < bestv || (ov == bestv && oj < bestj)) { bestv = ov; bestj = oj; }
        }
        minVal = bestv;
        const int jstar = bestj;
        if (lane == 0) s_SC[jstar] = 1;
        __syncthreads();
        const int rc = s_row4col[jstar];
        if (rc < 0) sink = jstar; else i = rc;
      }

      for (int r = lane; r < nv; r += 64)
        if (s_SRb[r] && r != cur)
          s_u[r] += minVal - s_shortest[s_col4row[r]];
      if (lane == 0) s_u[cur] += minVal;
      for (int j = lane; j < NS; j += 64)
        if (s_SC[j]) s_v[j] -= minVal - s_shortest[j];
      __syncthreads();

      if (lane == 0) {
        int j = sink;
        while (true) {
          const int i2 = s_path[j];
          s_row4col[j] = i2;
          const int nxt = s_col4row[i2];
          s_col4row[i2] = j;
          if (i2 == cur) break;
          j = nxt;
        }
      }
      __syncthreads();
    }

    double l1 = 0.0, sl1 = 0.0, wid = 0.0;
    for (int i = lane; i < nv; i += 64) {
      const int r = s_col4row[i];
      s_tc[r] = s_vlab[i];
      #pragma unroll
      for (int k = 0; k < 8; ++k) {
        const float d  = s_strokes[r * NP + k] - s_vt[i * NP + k];
        const float ad = fabsf(d);
        l1 += (double)ad;
        const float s = (ad < 0.1f) ? (0.5f * ad * ad / 0.1f) : (ad - 0.05f);
        sl1 += (double)s;
      }
      const float d8 = fabsf(s_strokes[r * NP + 8] - s_vt[i * NP + 8]);
      const float d9 = fabsf(s_strokes[r * NP + 9] - s_vt[i * NP + 9]);
      wid += (double)d8 + (double)d9;
    }
    l1 = wave_sum(l1); sl1 = wave_sum(sl1); wid = wave_sum(wid);
    if (lane == 0) {
      atomicAdd(&acc[2], l1);
      atomicAdd(&acc[3], sl1);
      atomicAdd(&acc[4], wid);
      atomicAdd(&acc[5], (double)nv);
    }
  }
  __syncthreads();

  double wnll = 0.0, wsum = 0.0;
  for (int s = lane; s < NS; s += 64) {
    const int tc = s_tc[s];
    const double x0 = (double)logits[(b * NS + s) * 3 + 0];
    const double x1 = (double)logits[(b * NS + s) * 3 + 1];
    const double x2 = (double)logits[(b * NS + s) * 3 + 2];
    const double m   = fmax(x0, fmax(x1, x2));
    const double lse = log(exp(x0 - m) + exp(x1 - m) + exp(x2 - m));
    const double xt  = (tc == 0) ? x0 : ((tc == 1) ? x1 : x2);
    const double nll = -(xt - m - lse);
    const double w   = (tc == 0) ? 0.1 : 1.0;
    wnll += w * nll;
    wsum += w;
  }
  wnll = wave_sum(wnll); wsum = wave_sum(wsum);
  if (lane == 0) {
    atomicAdd(&acc[0], wnll);
    atomicAdd(&acc[1], wsum);
  }
}

__global__ void detr_finalize_kernel(const double* __restrict__ acc,
                                     float* __restrict__ out) {
  const double loss_ce = acc[0] / acc[1];
  const double denom   = fmax(acc[5], 1.0);
  const double loss = 1.0 * loss_ce
                    + 5.0 * (acc[2] + acc[3]) / denom
                    + 2.0 * acc[4] / denom;
  out[0] = (float)loss;
}

extern "C" void kernel_launch(void* const* d_in, const int* in_sizes, int n_in,
                              void* d_out, int out_size, void* d_ws, size_t ws_size,
                              hipStream_t stream) {
  const float* strokes = (const float*)d_in[0];
  const float* logits  = (const float*)d_in[1];
  const float* tparams = (const float*)d_in[2];
  const int*   tlabels = (const int*)d_in[3];
  double* acc = (double*)d_ws;

  hipMemsetAsync(d_ws, 0, 64, stream);

  if (ws_size >= WS_NEEDED) {
    double* C = (double*)((char*)d_ws + WS_C_OFF);
    detr_cost_kernel<<<dim3(NB, 10), 256, 0, stream>>>(strokes, logits,
                                                       tparams, tlabels, C);
    detr_match_fast_kernel<<<NB, 64, 0, stream>>>(strokes, logits, tparams,
                                                  tlabels, C, acc);
  } else {
    detr_match_loss_kernel<<<NB, 64, 0, stream>>>(strokes, logits, tparams,
                                                  tlabels, acc);
  }
  detr_finalize_kernel<<<1, 1, 0, stream>>>(acc, (float*)d_out);
}

// Round 3
// 148.426 us; speedup vs baseline: 1.8264x; 1.4471x over previous
//
#include <hip/hip_runtime.h>
#include <math.h>
#include <stdint.h>

#define NB 128
#define NS 300   // pred slots (columns)
#define NG 100   // gt slots (max rows)
#define NP 10    // params per stroke
#define NSLOT 5  // ceil(NS/64)
#define KCACHE 24 // C rows cached in LDS (24*300*8 = 57600 B)

// ws layout: [0,64): acc doubles; [1024, 1024+128*100*300*8): cost matrix C
#define WS_C_OFF 1024
#define WS_NEEDED (WS_C_OFF + (size_t)NB * NG * NS * 8)

#define GET_SLOT(arr, slot, out) do { switch (slot) { \
  case 0: out = arr[0]; break; case 1: out = arr[1]; break; \
  case 2: out = arr[2]; break; case 3: out = arr[3]; break; \
  default: out = arr[4]; break; } } while (0)
#define SET_SLOT(arr, slot, val) do { switch (slot) { \
  case 0: arr[0] = val; break; case 1: arr[1] = val; break; \
  case 2: arr[2] = val; break; case 3: arr[3] = val; break; \
  default: arr[4] = val; break; } } while (0)

__device__ __forceinline__ double wave_sum(double v) {
  #pragma unroll
  for (int off = 32; off > 0; off >>= 1) v += __shfl_xor(v, off);
  return v;
}

// ---- order-preserving f64 <-> u64 key ----
__device__ __forceinline__ uint64_t pack_key(double d) {
  const uint64_t b = (uint64_t)__double_as_longlong(d);
  return (b >> 63) ? ~b : (b | 0x8000000000000000ull);
}
__device__ __forceinline__ double unpack_key(uint64_t k) {
  const uint64_t b = (k >> 63) ? (k & 0x7fffffffffffffffull) : ~k;
  return __longlong_as_double((long long)b);
}

// DPP shift/broadcast of a u64 across lanes; invalid source lanes yield
// 0xFFFF.. (min-identity). CDNA keeps row_bcast15/31.
template <int CTRL>
__device__ __forceinline__ uint64_t dpp_u64_or_max(uint64_t x) {
  const int lo = (int)(uint32_t)x;
  const int hi = (int)(uint32_t)(x >> 32);
  const int lo2 = __builtin_amdgcn_update_dpp(-1, lo, CTRL, 0xF, 0xF, false);
  const int hi2 = __builtin_amdgcn_update_dpp(-1, hi, CTRL, 0xF, 0xF, false);
  return ((uint64_t)(uint32_t)hi2 << 32) | (uint32_t)lo2;
}

// Wave argmin over per-lane (key, bestj). Returns exact min double and the
// winner's bestj (ties across lanes: lowest lane; exact f64 ties are
// measure-zero for this problem's random costs).
__device__ __forceinline__ void wave_argmin(uint64_t key, int bestj,
                                            double& minVal, int& jstar) {
  uint64_t k = key;
  { const uint64_t o = dpp_u64_or_max<0x111>(k); if (o < k) k = o; }  // row_shr:1
  { const uint64_t o = dpp_u64_or_max<0x112>(k); if (o < k) k = o; }  // row_shr:2
  { const uint64_t o = dpp_u64_or_max<0x114>(k); if (o < k) k = o; }  // row_shr:4
  { const uint64_t o = dpp_u64_or_max<0x118>(k); if (o < k) k = o; }  // row_shr:8
  { const uint64_t o = dpp_u64_or_max<0x142>(k); if (o < k) k = o; }  // row_bcast:15
  { const uint64_t o = dpp_u64_or_max<0x143>(k); if (o < k) k = o; }  // row_bcast:31
  const uint32_t mlo = (uint32_t)__builtin_amdgcn_readlane((int)(uint32_t)k, 63);
  const uint32_t mhi = (uint32_t)__builtin_amdgcn_readlane((int)(uint32_t)(k >> 32), 63);
  const uint64_t minkey = ((uint64_t)mhi << 32) | mlo;
  const unsigned long long winners = __ballot(key == minkey);
  const int src = __ffsll(winners) - 1;
  jstar = __builtin_amdgcn_readlane(bestj, src);
  minVal = unpack_key(minkey);
}

// ---------------------------------------------------------------------------
// Kernel B: precompute f64 cost matrix C[b][i][j] for valid rows i < nv.
// ---------------------------------------------------------------------------
__global__ __launch_bounds__(256) void detr_cost_kernel(
    const float* __restrict__ strokes,   // [B,300,10]
    const float* __restrict__ logits,    // [B,300,3]
    const float* __restrict__ tparams,   // [B,100,10]
    const int*   __restrict__ tlabels,   // [B,100]
    double*      __restrict__ C)         // [B,100,300]
{
  __shared__ float sS[NS * NP];
  __shared__ float sP[NS * 3];
  __shared__ float sVT[10 * NP];
  __shared__ int   sCls[10];
  __shared__ int   s_valid[NG];
  __shared__ int   s_vlab[NG];
  __shared__ int   s_nv;

  const int b   = blockIdx.x;
  const int cb  = blockIdx.y;
  const int tid = threadIdx.x;

  for (int idx = tid; idx < NS * NP; idx += 256)
    sS[idx] = strokes[b * NS * NP + idx];

  for (int j = tid; j < NS; j += 256) {
    const float x0 = logits[(b * NS + j) * 3 + 0];
    const float x1 = logits[(b * NS + j) * 3 + 1];
    const float x2 = logits[(b * NS + j) * 3 + 2];
    const float m  = fmaxf(x0, fmaxf(x1, x2));
    const float e0 = expf(x0 - m), e1 = expf(x1 - m), e2 = expf(x2 - m);
    const float s  = e0 + e1 + e2;
    sP[j * 3 + 0] = e0 / s;
    sP[j * 3 + 1] = e1 / s;
    sP[j * 3 + 2] = e2 / s;
  }

  if (tid < 64) {
    const unsigned long long below = (1ull << tid) - 1ull;
    const int lb1 = tlabels[b * NG + tid];
    const bool in2 = tid < (NG - 64);
    const int lb2 = in2 ? tlabels[b * NG + 64 + tid] : 0;
    const unsigned long long m1 = __ballot(lb1 > 0);
    const unsigned long long m2 = __ballot(in2 && lb2 > 0);
    const int c1 = __popcll(m1);
    if (lb1 > 0) {
      const int p = __popcll(m1 & below);
      s_valid[p] = tid; s_vlab[p] = lb1;
    }
    if (in2 && lb2 > 0) {
      const int p = c1 + __popcll(m2 & below);
      s_valid[p] = 64 + tid; s_vlab[p] = lb2;
    }
    if (tid == 0) s_nv = c1 + __popcll(m2);
  }
  __syncthreads();

  const int nv = s_nv;
  const int i0 = cb * 10;
  const int nrow = (nv - i0 < 10) ? (nv - i0) : 10;
  if (nrow <= 0) return;

  for (int idx = tid; idx < nrow * NP; idx += 256) {
    const int il = idx / NP, k = idx % NP;
    sVT[il * NP + k] = tparams[(b * NG + s_valid[i0 + il]) * NP + k];
  }
  if (tid < nrow) sCls[tid] = s_vlab[i0 + tid];
  __syncthreads();

  for (int e = tid; e < nrow * NS; e += 256) {
    const int il = e / NS, j = e - il * NS;
    const int cls = sCls[il];
    const double p = (double)sP[j * 3 + cls];
    double a[NP];
    #pragma unroll
    for (int k = 0; k < NP; ++k)
      a[k] = fabs((double)sS[j * NP + k] - (double)sVT[il * NP + k]);
    const double coord = ((a[0] + a[1]) + (a[2] + a[3])) +
                         ((a[4] + a[5]) + (a[6] + a[7]));
    const double c = -p + 5.0 * coord + 2.0 * (a[8] + a[9]) +
                     2.0 * (a[0] + a[1]);
    C[((size_t)b * NG + (i0 + il)) * NS + j] = c;
  }
}

// ---------------------------------------------------------------------------
// Kernel C: JV LAP, DPP argmin, register column state, LDS C-row cache.
// ---------------------------------------------------------------------------
__global__ __launch_bounds__(64) void detr_match_fast_kernel(
    const float* __restrict__ strokes,
    const float* __restrict__ logits,
    const float* __restrict__ tparams,
    const int*   __restrict__ tlabels,
    const double* __restrict__ C,
    double*      __restrict__ acc)
{
  __shared__ double s_crow[KCACHE * NS];  // 57600 B
  __shared__ int    s_valid[NG];
  __shared__ int    s_vlab[NG];
  __shared__ double s_u[NG];
  __shared__ int    s_col4row[NG];
  __shared__ double s_short[NS];
  __shared__ int    s_tc[NS];

  const int b    = blockIdx.x;
  const int lane = threadIdx.x;

  for (int j = lane; j < NS; j += 64) s_tc[j] = 0;

  // stable compaction via ballots (ascending g = np.where order)
  const unsigned long long below = (1ull << lane) - 1ull;
  const int lb1 = tlabels[b * NG + lane];
  const bool in2 = lane < (NG - 64);
  const int lb2 = in2 ? tlabels[b * NG + 64 + lane] : 0;
  const unsigned long long m1 = __ballot(lb1 > 0);
  const unsigned long long m2 = __ballot(in2 && lb2 > 0);
  const int c1 = __popcll(m1);
  if (lb1 > 0) {
    const int p = __popcll(m1 & below);
    s_valid[p] = lane; s_vlab[p] = lb1;
  }
  if (in2 && lb2 > 0) {
    const int p = c1 + __popcll(m2 & below);
    s_valid[p] = 64 + lane; s_vlab[p] = lb2;
  }
  const int nv = c1 + __popcll(m2);

  for (int i = lane; i < nv; i += 64) { s_u[i] = 0.0; s_col4row[i] = -1; }
  __syncthreads();

  if (nv > 0) {
    const double* Cb = C + (size_t)b * NG * NS;
    const double INF = (double)INFINITY;

    double vv[NSLOT];
    int    r4c[NSLOT];
    #pragma unroll
    for (int s = 0; s < NSLOT; ++s) { vv[s] = 0.0; r4c[s] = -1; }
    const int vmask = (lane < NS - 4 * 64) ? 0x1F : 0x0F;

    for (int cur = 0; cur < nv; ++cur) {
      // stage this augmentation's new row into the LDS cache
      if (cur < KCACHE) {
        for (int j = lane; j < NS; j += 64)
          s_crow[cur * NS + j] = Cb[(size_t)cur * NS + j];
      }
      __syncthreads();

      double sh[NSLOT];
      int    pa[NSLOT];
      #pragma unroll
      for (int s = 0; s < NSLOT; ++s) { sh[s] = INF; pa[s] = -1; }
      int scm = 0;
      unsigned long long srm0 = 0ull, srm1 = 0ull;  // SR bitmask (uniform)
      double minVal = 0.0;
      int i = cur;
      int sink = -1;

      while (sink == -1) {
        if (i < 64) srm0 |= (1ull << i); else srm1 |= (1ull << (i - 64));
        const double base = minVal - s_u[i];

        double cv[NSLOT];
        if (i < KCACHE) {
          const double* Lr = s_crow + i * NS;
          #pragma unroll
          for (int s = 0; s < NSLOT; ++s)
            if ((vmask >> s) & 1) cv[s] = Lr[lane + 64 * s];
        } else {
          const double* Gr = Cb + (size_t)i * NS;
          #pragma unroll
          for (int s = 0; s < NSLOT; ++s)
            if ((vmask >> s) & 1) cv[s] = Gr[lane + 64 * s];
        }

        double bestv = INF;
        int    bestj = 0x7fffffff;
        #pragma unroll
        for (int s = 0; s < NSLOT; ++s) {
          if ((vmask >> s) & 1) {
            if (!((scm >> s) & 1)) {
              const double d = base + cv[s] - vv[s];
              if (d < sh[s]) { sh[s] = d; pa[s] = i; }
              if (sh[s] < bestv) { bestv = sh[s]; bestj = lane + 64 * s; }
            }
          }
        }

        double mv; int jstar;
        wave_argmin(pack_key(bestv), bestj, mv, jstar);
        minVal = mv;
        const int slot = jstar >> 6;
        const int src  = jstar & 63;
        if (lane == src) scm |= (1 << slot);

        int t;
        GET_SLOT(r4c, slot, t);
        const int rc = __builtin_amdgcn_readlane(t, src);
        if (rc < 0) sink = jstar; else i = rc;
      }

      // expose shortest for dual updates
      #pragma unroll
      for (int s = 0; s < NSLOT; ++s)
        if ((vmask >> s) & 1) s_short[lane + 64 * s] = sh[s];
      __syncthreads();

      // u updates: lane handles rows `lane` and `lane+64` via SR bitmask
      if (lane < nv && lane != cur && ((srm0 >> lane) & 1ull))
        s_u[lane] += minVal - s_short[s_col4row[lane]];
      const int r2 = lane + 64;
      if (r2 < nv && r2 != cur && ((srm1 >> lane) & 1ull))
        s_u[r2] += minVal - s_short[s_col4row[r2]];
      if (lane == 0) s_u[cur] += minVal;
      #pragma unroll
      for (int s = 0; s < NSLOT; ++s)
        if ((scm >> s) & 1) vv[s] -= minVal - sh[s];
      __syncthreads();

      // augmenting-path flip (uniform walk, readlane gathers)
      int j = sink;
      while (true) {
        const int slot = j >> 6, src = j & 63;
        int t;
        GET_SLOT(pa, slot, t);
        const int i2 = __builtin_amdgcn_readlane(t, src);
        if (lane == src) SET_SLOT(r4c, slot, i2);
        const int nxt = s_col4row[i2];
        if (lane == 0) s_col4row[i2] = j;
        if (i2 == cur) break;
        j = nxt;
      }
      __syncthreads();
    }

    // matched regression partials + tc scatter (inputs read from global once)
    double l1 = 0.0, sl1 = 0.0, wid = 0.0;
    for (int i = lane; i < nv; i += 64) {
      const int r = s_col4row[i];
      s_tc[r] = s_vlab[i];
      const float* ps = strokes + ((size_t)b * NS + r) * NP;
      const float* tp = tparams + ((size_t)b * NG + s_valid[i]) * NP;
      #pragma unroll
      for (int k = 0; k < 8; ++k) {
        const float d  = ps[k] - tp[k];
        const float ad = fabsf(d);
        l1 += (double)ad;
        const float sm = (ad < 0.1f) ? (0.5f * ad * ad / 0.1f) : (ad - 0.05f);
        sl1 += (double)sm;
      }
      const float d8 = fabsf(ps[8] - tp[8]);
      const float d9 = fabsf(ps[9] - tp[9]);
      wid += (double)d8 + (double)d9;
    }
    l1 = wave_sum(l1); sl1 = wave_sum(sl1); wid = wave_sum(wid);
    if (lane == 0) {
      atomicAdd(&acc[2], l1);
      atomicAdd(&acc[3], sl1);
      atomicAdd(&acc[4], wid);
      atomicAdd(&acc[5], (double)nv);
    }
  }
  __syncthreads();

  // weighted CE over all 300 slots
  double wnll = 0.0, wsum = 0.0;
  for (int s = lane; s < NS; s += 64) {
    const int tc = s_tc[s];
    const double x0 = (double)logits[(b * NS + s) * 3 + 0];
    const double x1 = (double)logits[(b * NS + s) * 3 + 1];
    const double x2 = (double)logits[(b * NS + s) * 3 + 2];
    const double m   = fmax(x0, fmax(x1, x2));
    const double lse = log(exp(x0 - m) + exp(x1 - m) + exp(x2 - m));
    const double xt  = (tc == 0) ? x0 : ((tc == 1) ? x1 : x2);
    const double nll = -(xt - m - lse);
    const double w   = (tc == 0) ? 0.1 : 1.0;
    wnll += w * nll;
    wsum += w;
  }
  wnll = wave_sum(wnll); wsum = wave_sum(wsum);
  if (lane == 0) {
    atomicAdd(&acc[0], wnll);
    atomicAdd(&acc[1], wsum);
  }
}

// ---------------------------------------------------------------------------
// Fallback (ws too small): round-0 monolithic kernel.
// ---------------------------------------------------------------------------
__global__ __launch_bounds__(64) void detr_match_loss_kernel(
    const float* __restrict__ strokes,
    const float* __restrict__ logits,
    const float* __restrict__ tparams,
    const int*   __restrict__ tlabels,
    double*      __restrict__ acc)
{
  __shared__ float  s_strokes[NS * NP];
  __shared__ float  s_probs[NS * 3];
  __shared__ float  s_vt[NG * NP];
  __shared__ int    s_valid[NG];
  __shared__ int    s_vlab[NG];
  __shared__ double s_u[NG];
  __shared__ int    s_col4row[NG];
  __shared__ int    s_SRb[NG];
  __shared__ double s_shortest[NS];
  __shared__ double s_v[NS];
  __shared__ int    s_path[NS];
  __shared__ int    s_SC[NS];
  __shared__ int    s_row4col[NS];
  __shared__ int    s_tc[NS];
  __shared__ int    s_nv;

  const int b    = blockIdx.x;
  const int lane = threadIdx.x;

  for (int idx = lane; idx < NS * NP; idx += 64)
    s_strokes[idx] = strokes[b * NS * NP + idx];

  for (int j = lane; j < NS; j += 64) {
    const float x0 = logits[(b * NS + j) * 3 + 0];
    const float x1 = logits[(b * NS + j) * 3 + 1];
    const float x2 = logits[(b * NS + j) * 3 + 2];
    const float m  = fmaxf(x0, fmaxf(x1, x2));
    const float e0 = expf(x0 - m), e1 = expf(x1 - m), e2 = expf(x2 - m);
    const float s  = e0 + e1 + e2;
    s_probs[j * 3 + 0] = e0 / s;
    s_probs[j * 3 + 1] = e1 / s;
    s_probs[j * 3 + 2] = e2 / s;
    s_tc[j]      = 0;
    s_row4col[j] = -1;
    s_v[j]       = 0.0;
  }

  if (lane == 0) {
    int nv = 0;
    for (int g = 0; g < NG; ++g) {
      const int lb = tlabels[b * NG + g];
      if (lb > 0) { s_valid[nv] = g; s_vlab[nv] = lb; ++nv; }
    }
    s_nv = nv;
  }
  __syncthreads();
  const int nv = s_nv;

  for (int idx = lane; idx < nv * NP; idx += 64) {
    const int i = idx / NP, k = idx % NP;
    s_vt[idx] = tparams[(b * NG + s_valid[i]) * NP + k];
  }
  for (int i = lane; i < nv; i += 64) { s_u[i] = 0.0; s_col4row[i] = -1; }
  __syncthreads();

  if (nv > 0) {
    for (int cur = 0; cur < nv; ++cur) {
      for (int j = lane; j < NS; j += 64) {
        s_shortest[j] = 1e300;
        s_path[j]     = -1;
        s_SC[j]       = 0;
      }
      for (int r = lane; r < nv; r += 64) s_SRb[r] = 0;
      __syncthreads();

      double minVal = 0.0;
      int i = cur;
      int sink = -1;

      while (sink == -1) {
        if (lane == 0) s_SRb[i] = 1;
        const double ui  = s_u[i];
        const int    cls = s_vlab[i];
        double vtr[NP];
        #pragma unroll
        for (int k = 0; k < NP; ++k) vtr[k] = (double)s_vt[i * NP + k];
        const double base = minVal - ui;

        double bestv = 1e300;
        int    bestj = 0x7fffffff;

        for (int j = lane; j < NS; j += 64) {
          if (!s_SC[j]) {
            const double p = (double)s_probs[j * 3 + cls];
            double a[NP];
            #pragma unroll
            for (int k = 0; k < NP; ++k)
              a[k] = fabs((double)s_strokes[j * NP + k] - vtr[k]);
            const double coord = ((a[0] + a[1]) + (a[2] + a[3])) +
                                 ((a[4] + a[5]) + (a[6] + a[7]));
            const double c = -p + 5.0 * coord + 2.0 * (a[8] + a[9]) +
                             2.0 * (a[0] + a[1]);
            const double d = base + c - s_v[j];
            if (d < s_shortest[j]) { s_shortest[j] = d; s_path[j] = i; }
            const double sv = s_shortest[j];
            if (sv < bestv) { bestv = sv; bestj = j; }
          }
        }

        #pragma unroll
        for (int off = 32; off > 0; off >>= 1) {
          const double ov = __shfl_xor(bestv, off);
          const int    oj = __shfl_xor(bestj, off);
          if (ov < bestv || (ov == bestv && oj < bestj)) { bestv = ov; bestj = oj; }
        }
        minVal = bestv;
        const int jstar = bestj;
        if (lane == 0) s_SC[jstar] = 1;
        __syncthreads();
        const int rc = s_row4col[jstar];
        if (rc < 0) sink = jstar; else i = rc;
      }

      for (int r = lane; r < nv; r += 64)
        if (s_SRb[r] && r != cur)
          s_u[r] += minVal - s_shortest[s_col4row[r]];
      if (lane == 0) s_u[cur] += minVal;
      for (int j = lane; j < NS; j += 64)
        if (s_SC[j]) s_v[j] -= minVal - s_shortest[j];
      __syncthreads();

      if (lane == 0) {
        int j = sink;
        while (true) {
          const int i2 = s_path[j];
          s_row4col[j] = i2;
          const int nxt = s_col4row[i2];
          s_col4row[i2] = j;
          if (i2 == cur) break;
          j = nxt;
        }
      }
      __syncthreads();
    }

    double l1 = 0.0, sl1 = 0.0, wid = 0.0;
    for (int i = lane; i < nv; i += 64) {
      const int r = s_col4row[i];
      s_tc[r] = s_vlab[i];
      #pragma unroll
      for (int k = 0; k < 8; ++k) {
        const float d  = s_strokes[r * NP + k] - s_vt[i * NP + k];
        const float ad = fabsf(d);
        l1 += (double)ad;
        const float s = (ad < 0.1f) ? (0.5f * ad * ad / 0.1f) : (ad - 0.05f);
        sl1 += (double)s;
      }
      const float d8 = fabsf(s_strokes[r * NP + 8] - s_vt[i * NP + 8]);
      const float d9 = fabsf(s_strokes[r * NP + 9] - s_vt[i * NP + 9]);
      wid += (double)d8 + (double)d9;
    }
    l1 = wave_sum(l1); sl1 = wave_sum(sl1); wid = wave_sum(wid);
    if (lane == 0) {
      atomicAdd(&acc[2], l1);
      atomicAdd(&acc[3], sl1);
      atomicAdd(&acc[4], wid);
      atomicAdd(&acc[5], (double)nv);
    }
  }
  __syncthreads();

  double wnll = 0.0, wsum = 0.0;
  for (int s = lane; s < NS; s += 64) {
    const int tc = s_tc[s];
    const double x0 = (double)logits[(b * NS + s) * 3 + 0];
    const double x1 = (double)logits[(b * NS + s) * 3 + 1];
    const double x2 = (double)logits[(b * NS + s) * 3 + 2];
    const double m   = fmax(x0, fmax(x1, x2));
    const double lse = log(exp(x0 - m) + exp(x1 - m) + exp(x2 - m));
    const double xt  = (tc == 0) ? x0 : ((tc == 1) ? x1 : x2);
    const double nll = -(xt - m - lse);
    const double w   = (tc == 0) ? 0.1 : 1.0;
    wnll += w * nll;
    wsum += w;
  }
  wnll = wave_sum(wnll); wsum = wave_sum(wsum);
  if (lane == 0) {
    atomicAdd(&acc[0], wnll);
    atomicAdd(&acc[1], wsum);
  }
}

__global__ void detr_finalize_kernel(const double* __restrict__ acc,
                                     float* __restrict__ out) {
  const double loss_ce = acc[0] / acc[1];
  const double denom   = fmax(acc[5], 1.0);
  const double loss = 1.0 * loss_ce
                    + 5.0 * (acc[2] + acc[3]) / denom
                    + 2.0 * acc[4] / denom;
  out[0] = (float)loss;
}

extern "C" void kernel_launch(void* const* d_in, const int* in_sizes, int n_in,
                              void* d_out, int out_size, void* d_ws, size_t ws_size,
                              hipStream_t stream) {
  const float* strokes = (const float*)d_in[0];
  const float* logits  = (const float*)d_in[1];
  const float* tparams = (const float*)d_in[2];
  const int*   tlabels = (const int*)d_in[3];
  double* acc = (double*)d_ws;

  hipMemsetAsync(d_ws, 0, 64, stream);

  if (ws_size >= WS_NEEDED) {
    double* C = (double*)((char*)d_ws + WS_C_OFF);
    detr_cost_kernel<<<dim3(NB, 10), 256, 0, stream>>>(strokes, logits,
                                                       tparams, tlabels, C);
    detr_match_fast_kernel<<<NB, 64, 0, stream>>>(strokes, logits, tparams,
                                                  tlabels, C, acc);
  } else {
    detr_match_loss_kernel<<<NB, 64, 0, stream>>>(strokes, logits, tparams,
                                                  tlabels, acc);
  }
  detr_finalize_kernel<<<1, 1, 0, stream>>>(acc, (float*)d_out);
}

// Round 5
// 85.162 us; speedup vs baseline: 3.1832x; 1.7429x over previous
//
#include <hip/hip_runtime.h>
#include <math.h>
#include <stdint.h>

#define NB 128
#define NS 300   // pred slots (columns)
#define NG 100   // gt slots (max rows)
#define NP 10    // params per stroke
#define NSLOT 5  // ceil(NS/64)

// ws layout: [0,64): acc doubles; [1024, 1024+128*100*300*8): cost matrix C
#define WS_C_OFF 1024
#define WS_NEEDED (WS_C_OFF + (size_t)NB * NG * NS * 8)

#define GET_SLOT(arr, slot, out) do { switch (slot) { \
  case 0: out = arr[0]; break; case 1: out = arr[1]; break; \
  case 2: out = arr[2]; break; case 3: out = arr[3]; break; \
  default: out = arr[4]; break; } } while (0)
#define SET_SLOT(arr, slot, val) do { switch (slot) { \
  case 0: arr[0] = val; break; case 1: arr[1] = val; break; \
  case 2: arr[2] = val; break; case 3: arr[3] = val; break; \
  default: arr[4] = val; break; } } while (0)

__device__ __forceinline__ double wave_sum(double v) {
  #pragma unroll
  for (int off = 32; off > 0; off >>= 1) v += __shfl_xor(v, off);
  return v;
}

// ---- order-preserving f64 <-> u64 key ----
__device__ __forceinline__ uint64_t pack_key(double d) {
  const uint64_t b = (uint64_t)__double_as_longlong(d);
  return (b >> 63) ? ~b : (b | 0x8000000000000000ull);
}
__device__ __forceinline__ double unpack_key(uint64_t k) {
  const uint64_t b = (k >> 63) ? (k & 0x7fffffffffffffffull) : ~k;
  return __longlong_as_double((long long)b);
}

__device__ __forceinline__ double rl_f64(double v, int src) {
  const uint64_t b = (uint64_t)__double_as_longlong(v);
  const int lo = __builtin_amdgcn_readlane((int)(uint32_t)b, src);
  const int hi = __builtin_amdgcn_readlane((int)(uint32_t)(b >> 32), src);
  return __longlong_as_double((long long)(((uint64_t)(uint32_t)hi << 32) |
                                          (uint32_t)lo));
}

template <int CTRL>
__device__ __forceinline__ uint64_t dpp_u64_or_max(uint64_t x) {
  const int lo = (int)(uint32_t)x;
  const int hi = (int)(uint32_t)(x >> 32);
  const int lo2 = __builtin_amdgcn_update_dpp(-1, lo, CTRL, 0xF, 0xF, false);
  const int hi2 = __builtin_amdgcn_update_dpp(-1, hi, CTRL, 0xF, 0xF, false);
  return ((uint64_t)(uint32_t)hi2 << 32) | (uint32_t)lo2;
}

__device__ __forceinline__ void wave_argmin(uint64_t key, int bestj,
                                            double& minVal, int& jstar) {
  uint64_t k = key;
  { const uint64_t o = dpp_u64_or_max<0x111>(k); if (o < k) k = o; }
  { const uint64_t o = dpp_u64_or_max<0x112>(k); if (o < k) k = o; }
  { const uint64_t o = dpp_u64_or_max<0x114>(k); if (o < k) k = o; }
  { const uint64_t o = dpp_u64_or_max<0x118>(k); if (o < k) k = o; }
  { const uint64_t o = dpp_u64_or_max<0x142>(k); if (o < k) k = o; }
  { const uint64_t o = dpp_u64_or_max<0x143>(k); if (o < k) k = o; }
  const uint32_t mlo = (uint32_t)__builtin_amdgcn_readlane((int)(uint32_t)k, 63);
  const uint32_t mhi = (uint32_t)__builtin_amdgcn_readlane((int)(uint32_t)(k >> 32), 63);
  const uint64_t minkey = ((uint64_t)mhi << 32) | mlo;
  const unsigned long long winners = __ballot(key == minkey);
  const int src = __ffsll(winners) - 1;
  jstar = __builtin_amdgcn_readlane(bestj, src);
  minVal = unpack_key(minkey);
}

// ---------------------------------------------------------------------------
// Kernel B: precompute f64 cost matrix C[b][i][j] for valid rows i < nv.
// ---------------------------------------------------------------------------
__global__ __launch_bounds__(256) void detr_cost_kernel(
    const float* __restrict__ strokes,
    const float* __restrict__ logits,
    const float* __restrict__ tparams,
    const int*   __restrict__ tlabels,
    double*      __restrict__ C)
{
  __shared__ float sS[NS * NP];
  __shared__ float sP[NS * 3];
  __shared__ float sVT[10 * NP];
  __shared__ int   sCls[10];
  __shared__ int   s_valid[NG];
  __shared__ int   s_vlab[NG];
  __shared__ int   s_nv;

  const int b   = blockIdx.x;
  const int cb  = blockIdx.y;
  const int tid = threadIdx.x;

  for (int idx = tid; idx < NS * NP; idx += 256)
    sS[idx] = strokes[b * NS * NP + idx];

  for (int j = tid; j < NS; j += 256) {
    const float x0 = logits[(b * NS + j) * 3 + 0];
    const float x1 = logits[(b * NS + j) * 3 + 1];
    const float x2 = logits[(b * NS + j) * 3 + 2];
    const float m  = fmaxf(x0, fmaxf(x1, x2));
    const float e0 = expf(x0 - m), e1 = expf(x1 - m), e2 = expf(x2 - m);
    const float s  = e0 + e1 + e2;
    sP[j * 3 + 0] = e0 / s;
    sP[j * 3 + 1] = e1 / s;
    sP[j * 3 + 2] = e2 / s;
  }

  if (tid < 64) {
    const unsigned long long below = (1ull << tid) - 1ull;
    const int lb1 = tlabels[b * NG + tid];
    const bool in2 = tid < (NG - 64);
    const int lb2 = in2 ? tlabels[b * NG + 64 + tid] : 0;
    const unsigned long long m1 = __ballot(lb1 > 0);
    const unsigned long long m2 = __ballot(in2 && lb2 > 0);
    const int c1 = __popcll(m1);
    if (lb1 > 0) {
      const int p = __popcll(m1 & below);
      s_valid[p] = tid; s_vlab[p] = lb1;
    }
    if (in2 && lb2 > 0) {
      const int p = c1 + __popcll(m2 & below);
      s_valid[p] = 64 + tid; s_vlab[p] = lb2;
    }
    if (tid == 0) s_nv = c1 + __popcll(m2);
  }
  __syncthreads();

  const int nv = s_nv;
  const int i0 = cb * 10;
  const int nrow = (nv - i0 < 10) ? (nv - i0) : 10;
  if (nrow <= 0) return;

  for (int idx = tid; idx < nrow * NP; idx += 256) {
    const int il = idx / NP, k = idx % NP;
    sVT[il * NP + k] = tparams[(b * NG + s_valid[i0 + il]) * NP + k];
  }
  if (tid < nrow) sCls[tid] = s_vlab[i0 + tid];
  __syncthreads();

  for (int e = tid; e < nrow * NS; e += 256) {
    const int il = e / NS, j = e - il * NS;
    const int cls = sCls[il];
    const double p = (double)sP[j * 3 + cls];
    double a[NP];
    #pragma unroll
    for (int k = 0; k < NP; ++k)
      a[k] = fabs((double)sS[j * NP + k] - (double)sVT[il * NP + k]);
    const double coord = ((a[0] + a[1]) + (a[2] + a[3])) +
                         ((a[4] + a[5]) + (a[6] + a[7]));
    const double c = -p + 5.0 * coord + 2.0 * (a[8] + a[9]) +
                     2.0 * (a[0] + a[1]);
    C[((size_t)b * NG + (i0 + il)) * NS + j] = c;
  }
}

// ---------------------------------------------------------------------------
// Kernel C: JV LAP with ROW-reduction warm start (u = row minima, v = 0 —
// valid rectangular duals: v <= 0, free columns v = 0) + greedy tight claims
// + SAP augmentation for conflict rows. Exact optimum (unique a.s.).
// ---------------------------------------------------------------------------
__global__ __launch_bounds__(64) void detr_match_fast_kernel(
    const float* __restrict__ strokes,
    const float* __restrict__ logits,
    const float* __restrict__ tparams,
    const int*   __restrict__ tlabels,
    const double* __restrict__ C,
    double*      __restrict__ acc)
{
  __shared__ int    s_valid[NG];
  __shared__ int    s_vlab[NG];
  __shared__ int    s_col4row[NG];
  __shared__ int    s_claimC[NS];
  __shared__ int    s_r4cL[NS];
  __shared__ double s_short[NS];
  __shared__ int    s_tc[NS];

  const int b    = blockIdx.x;
  const int lane = threadIdx.x;

  for (int j = lane; j < NS; j += 64) {
    s_tc[j] = 0; s_claimC[j] = 0x7fffffff; s_r4cL[j] = -1;
  }

  // stable compaction via ballots (ascending g = np.where order)
  const unsigned long long below = (1ull << lane) - 1ull;
  const int lb1 = tlabels[b * NG + lane];
  const bool in2 = lane < (NG - 64);
  const int lb2 = in2 ? tlabels[b * NG + 64 + lane] : 0;
  const unsigned long long m1 = __ballot(lb1 > 0);
  const unsigned long long m2 = __ballot(in2 && lb2 > 0);
  const int c1 = __popcll(m1);
  if (lb1 > 0) {
    const int p = __popcll(m1 & below);
    s_valid[p] = lane; s_vlab[p] = lb1;
  }
  if (in2 && lb2 > 0) {
    const int p = c1 + __popcll(m2 & below);
    s_valid[p] = 64 + lane; s_vlab[p] = lb2;
  }
  const int nv = c1 + __popcll(m2);

  for (int i = lane; i < nv; i += 64) s_col4row[i] = -1;
  __syncthreads();

  if (nv > 0) {
    const double* Cb = C + (size_t)b * NG * NS;
    const double INF = (double)INFINITY;
    const int vmask = (lane < NS - 4 * 64) ? 0x1F : 0x0F;

    // ---- row reduction: u[i] = min_j C[i][j], argmin col per row ----
    // lane handles rows `lane` and `lane+64` (double2 streaming scan)
    double rm0 = INF; int ra0 = -1;
    if (lane < nv) {
      const double2* r = (const double2*)(Cb + (size_t)lane * NS);
      for (int h = 0; h < NS / 2; ++h) {
        const double2 v2 = r[h];
        if (v2.x < rm0) { rm0 = v2.x; ra0 = 2 * h; }
        if (v2.y < rm0) { rm0 = v2.y; ra0 = 2 * h + 1; }
      }
    }
    double rm1 = INF; int ra1 = -1;
    if (lane + 64 < nv) {
      const double2* r = (const double2*)(Cb + (size_t)(lane + 64) * NS);
      for (int h = 0; h < NS / 2; ++h) {
        const double2 v2 = r[h];
        if (v2.x < rm1) { rm1 = v2.x; ra1 = 2 * h; }
        if (v2.y < rm1) { rm1 = v2.y; ra1 = 2 * h + 1; }
      }
    }

    // ---- greedy tight claims: lowest row index wins a contested column ----
    if (lane < nv)      atomicMin(&s_claimC[ra0], lane);
    if (lane + 64 < nv) atomicMin(&s_claimC[ra1], lane + 64);
    __syncthreads();
    if (lane < nv && s_claimC[ra0] == lane) {
      s_r4cL[ra0] = lane; s_col4row[lane] = ra0;
    }
    if (lane + 64 < nv && s_claimC[ra1] == lane + 64) {
      s_r4cL[ra1] = lane + 64; s_col4row[lane + 64] = ra1;
    }
    __syncthreads();

    // register column state
    int r4c[NSLOT];
    #pragma unroll
    for (int s = 0; s < NSLOT; ++s)
      r4c[s] = ((vmask >> s) & 1) ? s_r4cL[lane + 64 * s] : -1;
    double vv[NSLOT];
    #pragma unroll
    for (int s = 0; s < NSLOT; ++s) vv[s] = 0.0;

    // u duals in registers (warm-started to row minima)
    double u0 = (lane < nv) ? rm0 : 0.0;
    double u1 = (lane + 64 < nv) ? rm1 : 0.0;

    // free rows = claim losers
    unsigned long long f0 = __ballot(lane < nv && s_col4row[lane] < 0);
    unsigned long long f1 = __ballot(lane + 64 < nv && s_col4row[lane + 64] < 0);

    while (f0 | f1) {
      int cur;
      if (f0) { cur = __ffsll(f0) - 1; f0 &= f0 - 1; }
      else    { cur = 64 + __ffsll(f1) - 1; f1 &= f1 - 1; }

      double sh[NSLOT];
      int    pa[NSLOT];
      #pragma unroll
      for (int s = 0; s < NSLOT; ++s) { sh[s] = INF; pa[s] = -1; }
      int scm = 0;
      unsigned long long srm0 = 0ull, srm1 = 0ull;
      double minVal = 0.0;
      int i = cur;
      int sink = -1;

      while (sink == -1) {
        if (i < 64) srm0 |= (1ull << i); else srm1 |= (1ull << (i - 64));
        const double ucur = (i < 64) ? rl_f64(u0, i) : rl_f64(u1, i - 64);
        const double base = minVal - ucur;
        const double* Gr = Cb + (size_t)i * NS;

        double bestv = INF;
        int    bestj = 0x7fffffff;
        #pragma unroll
        for (int s = 0; s < NSLOT; ++s) {
          if ((vmask >> s) & 1) {
            const double c = Gr[lane + 64 * s];
            if (!((scm >> s) & 1)) {
              const double d = base + c - vv[s];
              if (d < sh[s]) { sh[s] = d; pa[s] = i; }
              if (sh[s] < bestv) { bestv = sh[s]; bestj = lane + 64 * s; }
            }
          }
        }

        double mv; int jstar;
        wave_argmin(pack_key(bestv), bestj, mv, jstar);
        minVal = mv;
        const int slot = jstar >> 6;
        const int src  = jstar & 63;
        if (lane == src) scm |= (1 << slot);

        int t;
        GET_SLOT(r4c, slot, t);
        const int rc = __builtin_amdgcn_readlane(t, src);
        if (rc < 0) sink = jstar; else i = rc;
      }

      // expose shortest for dual updates
      #pragma unroll
      for (int s = 0; s < NSLOT; ++s)
        if ((vmask >> s) & 1) s_short[lane + 64 * s] = sh[s];
      __syncthreads();

      if (((srm0 >> lane) & 1ull) && lane != cur)
        u0 += minVal - s_short[s_col4row[lane]];
      const int r2 = lane + 64;
      if (((srm1 >> lane) & 1ull) && r2 != cur)
        u1 += minVal - s_short[s_col4row[r2]];
      if (lane == cur) u0 += minVal;
      if (r2 == cur)   u1 += minVal;
      #pragma unroll
      for (int s = 0; s < NSLOT; ++s)
        if ((scm >> s) & 1) vv[s] -= minVal - sh[s];
      __syncthreads();

      // augmenting-path flip
      int j = sink;
      while (true) {
        const int slot = j >> 6, src = j & 63;
        int t;
        GET_SLOT(pa, slot, t);
        const int i2 = __builtin_amdgcn_readlane(t, src);
        if (lane == src) SET_SLOT(r4c, slot, i2);
        const int nxt = s_col4row[i2];
        if (lane == 0) s_col4row[i2] = j;
        if (i2 == cur) break;
        j = nxt;
      }
      __syncthreads();
    }

    // matched regression partials + tc scatter
    double l1 = 0.0, sl1 = 0.0, wid = 0.0;
    for (int i = lane; i < nv; i += 64) {
      const int r = s_col4row[i];
      s_tc[r] = s_vlab[i];
      const float* ps = strokes + ((size_t)b * NS + r) * NP;
      const float* tp = tparams + ((size_t)b * NG + s_valid[i]) * NP;
      #pragma unroll
      for (int k = 0; k < 8; ++k) {
        const float d  = ps[k] - tp[k];
        const float ad = fabsf(d);
        l1 += (double)ad;
        const float sm = (ad < 0.1f) ? (0.5f * ad * ad / 0.1f) : (ad - 0.05f);
        sl1 += (double)sm;
      }
      const float d8 = fabsf(ps[8] - tp[8]);
      const float d9 = fabsf(ps[9] - tp[9]);
      wid += (double)d8 + (double)d9;
    }
    l1 = wave_sum(l1); sl1 = wave_sum(sl1); wid = wave_sum(wid);
    if (lane == 0) {
      atomicAdd(&acc[2], l1);
      atomicAdd(&acc[3], sl1);
      atomicAdd(&acc[4], wid);
      atomicAdd(&acc[5], (double)nv);
    }
  }
  __syncthreads();

  // weighted CE over all 300 slots
  double wnll = 0.0, wsum = 0.0;
  for (int s = lane; s < NS; s += 64) {
    const int tc = s_tc[s];
    const double x0 = (double)logits[(b * NS + s) * 3 + 0];
    const double x1 = (double)logits[(b * NS + s) * 3 + 1];
    const double x2 = (double)logits[(b * NS + s) * 3 + 2];
    const double m   = fmax(x0, fmax(x1, x2));
    const double lse = log(exp(x0 - m) + exp(x1 - m) + exp(x2 - m));
    const double xt  = (tc == 0) ? x0 : ((tc == 1) ? x1 : x2);
    const double nll = -(xt - m - lse);
    const double w   = (tc == 0) ? 0.1 : 1.0;
    wnll += w * nll;
    wsum += w;
  }
  wnll = wave_sum(wnll); wsum = wave_sum(wsum);
  if (lane == 0) {
    atomicAdd(&acc[0], wnll);
    atomicAdd(&acc[1], wsum);
  }
}

// ---------------------------------------------------------------------------
// Fallback (ws too small): round-0 monolithic kernel (proven, absmax 0.0).
// ---------------------------------------------------------------------------
__global__ __launch_bounds__(64) void detr_match_loss_kernel(
    const float* __restrict__ strokes,
    const float* __restrict__ logits,
    const float* __restrict__ tparams,
    const int*   __restrict__ tlabels,
    double*      __restrict__ acc)
{
  __shared__ float  s_strokes[NS * NP];
  __shared__ float  s_probs[NS * 3];
  __shared__ float  s_vt[NG * NP];
  __shared__ int    s_valid[NG];
  __shared__ int    s_vlab[NG];
  __shared__ double s_u[NG];
  __shared__ int    s_col4row[NG];
  __shared__ int    s_SRb[NG];
  __shared__ double s_shortest[NS];
  __shared__ double s_v[NS];
  __shared__ int    s_path[NS];
  __shared__ int    s_SC[NS];
  __shared__ int    s_row4col[NS];
  __shared__ int    s_tc[NS];
  __shared__ int    s_nv;

  const int b    = blockIdx.x;
  const int lane = threadIdx.x;

  for (int idx = lane; idx < NS * NP; idx += 64)
    s_strokes[idx] = strokes[b * NS * NP + idx];

  for (int j = lane; j < NS; j += 64) {
    const float x0 = logits[(b * NS + j) * 3 + 0];
    const float x1 = logits[(b * NS + j) * 3 + 1];
    const float x2 = logits[(b * NS + j) * 3 + 2];
    const float m  = fmaxf(x0, fmaxf(x1, x2));
    const float e0 = expf(x0 - m), e1 = expf(x1 - m), e2 = expf(x2 - m);
    const float s  = e0 + e1 + e2;
    s_probs[j * 3 + 0] = e0 / s;
    s_probs[j * 3 + 1] = e1 / s;
    s_probs[j * 3 + 2] = e2 / s;
    s_tc[j]      = 0;
    s_row4col[j] = -1;
    s_v[j]       = 0.0;
  }

  if (lane == 0) {
    int nv = 0;
    for (int g = 0; g < NG; ++g) {
      const int lb = tlabels[b * NG + g];
      if (lb > 0) { s_valid[nv] = g; s_vlab[nv] = lb; ++nv; }
    }
    s_nv = nv;
  }
  __syncthreads();
  const int nv = s_nv;

  for (int idx = lane; idx < nv * NP; idx += 64) {
    const int i = idx / NP, k = idx % NP;
    s_vt[idx] = tparams[(b * NG + s_valid[i]) * NP + k];
  }
  for (int i = lane; i < nv; i += 64) { s_u[i] = 0.0; s_col4row[i] = -1; }
  __syncthreads();

  if (nv > 0) {
    for (int cur = 0; cur < nv; ++cur) {
      for (int j = lane; j < NS; j += 64) {
        s_shortest[j] = 1e300;
        s_path[j]     = -1;
        s_SC[j]       = 0;
      }
      for (int r = lane; r < nv; r += 64) s_SRb[r] = 0;
      __syncthreads();

      double minVal = 0.0;
      int i = cur;
      int sink = -1;

      while (sink == -1) {
        if (lane == 0) s_SRb[i] = 1;
        const double ui  = s_u[i];
        const int    cls = s_vlab[i];
        double vtr[NP];
        #pragma unroll
        for (int k = 0; k < NP; ++k) vtr[k] = (double)s_vt[i * NP + k];
        const double base = minVal - ui;

        double bestv = 1e300;
        int    bestj = 0x7fffffff;

        for (int j = lane; j < NS; j += 64) {
          if (!s_SC[j]) {
            const double p = (double)s_probs[j * 3 + cls];
            double a[NP];
            #pragma unroll
            for (int k = 0; k < NP; ++k)
              a[k] = fabs((double)s_strokes[j * NP + k] - vtr[k]);
            const double coord = ((a[0] + a[1]) + (a[2] + a[3])) +
                                 ((a[4] + a[5]) + (a[6] + a[7]));
            const double c = -p + 5.0 * coord + 2.0 * (a[8] + a[9]) +
                             2.0 * (a[0] + a[1]);
            const double d = base + c - s_v[j];
            if (d < s_shortest[j]) { s_shortest[j] = d; s_path[j] = i; }
            const double sv = s_shortest[j];
            if (sv < bestv) { bestv = sv; bestj = j; }
          }
        }

        #pragma unroll
        for (int off = 32; off > 0; off >>= 1) {
          const double ov = __shfl_xor(bestv, off);
          const int    oj = __shfl_xor(bestj, off);
          if (ov < bestv || (ov == bestv && oj < bestj)) { bestv = ov; bestj = oj; }
        }
        minVal = bestv;
        const int jstar = bestj;
        if (lane == 0) s_SC[jstar] = 1;
        __syncthreads();
        const int rc = s_row4col[jstar];
        if (rc < 0) sink = jstar; else i = rc;
      }

      for (int r = lane; r < nv; r += 64)
        if (s_SRb[r] && r != cur)
          s_u[r] += minVal - s_shortest[s_col4row[r]];
      if (lane == 0) s_u[cur] += minVal;
      for (int j = lane; j < NS; j += 64)
        if (s_SC[j]) s_v[j] -= minVal - s_shortest[j];
      __syncthreads();

      if (lane == 0) {
        int j = sink;
        while (true) {
          const int i2 = s_path[j];
          s_row4col[j] = i2;
          const int nxt = s_col4row[i2];
          s_col4row[i2] = j;
          if (i2 == cur) break;
          j = nxt;
        }
      }
      __syncthreads();
    }

    double l1 = 0.0, sl1 = 0.0, wid = 0.0;
    for (int i = lane; i < nv; i += 64) {
      const int r = s_col4row[i];
      s_tc[r] = s_vlab[i];
      #pragma unroll
      for (int k = 0; k < 8; ++k) {
        const float d  = s_strokes[r * NP + k] - s_vt[i * NP + k];
        const float ad = fabsf(d);
        l1 += (double)ad;
        const float s = (ad < 0.1f) ? (0.5f * ad * ad / 0.1f) : (ad - 0.05f);
        sl1 += (double)s;
      }
      const float d8 = fabsf(s_strokes[r * NP + 8] - s_vt[i * NP + 8]);
      const float d9 = fabsf(s_strokes[r * NP + 9] - s_vt[i * NP + 9]);
      wid += (double)d8 + (double)d9;
    }
    l1 = wave_sum(l1); sl1 = wave_sum(sl1); wid = wave_sum(wid);
    if (lane == 0) {
      atomicAdd(&acc[2], l1);
      atomicAdd(&acc[3], sl1);
      atomicAdd(&acc[4], wid);
      atomicAdd(&acc[5], (double)nv);
    }
  }
  __syncthreads();

  double wnll = 0.0, wsum = 0.0;
  for (int s = lane; s < NS; s += 64) {
    const int tc = s_tc[s];
    const double x0 = (double)logits[(b * NS + s) * 3 + 0];
    const double x1 = (double)logits[(b * NS + s) * 3 + 1];
    const double x2 = (double)logits[(b * NS + s) * 3 + 2];
    const double m   = fmax(x0, fmax(x1, x2));
    const double lse = log(exp(x0 - m) + exp(x1 - m) + exp(x2 - m));
    const double xt  = (tc == 0) ? x0 : ((tc == 1) ? x1 : x2);
    const double nll = -(xt - m - lse);
    const double w   = (tc == 0) ? 0.1 : 1.0;
    wnll += w * nll;
    wsum += w;
  }
  wnll = wave_sum(wnll); wsum = wave_sum(wsum);
  if (lane == 0) {
    atomicAdd(&acc[0], wnll);
    atomicAdd(&acc[1], wsum);
  }
}

__global__ void detr_finalize_kernel(const double* __restrict__ acc,
                                     float* __restrict__ out) {
  const double loss_ce = acc[0] / acc[1];
  const double denom   = fmax(acc[5], 1.0);
  const double loss = 1.0 * loss_ce
                    + 5.0 * (acc[2] + acc[3]) / denom
                    + 2.0 * acc[4] / denom;
  out[0] = (float)loss;
}

extern "C" void kernel_launch(void* const* d_in, const int* in_sizes, int n_in,
                              void* d_out, int out_size, void* d_ws, size_t ws_size,
                              hipStream_t stream) {
  const float* strokes = (const float*)d_in[0];
  const float* logits  = (const float*)d_in[1];
  const float* tparams = (const float*)d_in[2];
  const int*   tlabels = (const int*)d_in[3];
  double* acc = (double*)d_ws;

  hipMemsetAsync(d_ws, 0, 64, stream);

  if (ws_size >= WS_NEEDED) {
    double* C = (double*)((char*)d_ws + WS_C_OFF);
    detr_cost_kernel<<<dim3(NB, 10), 256, 0, stream>>>(strokes, logits,
                                                       tparams, tlabels, C);
    detr_match_fast_kernel<<<NB, 64, 0, stream>>>(strokes, logits, tparams,
                                                  tlabels, C, acc);
  } else {
    detr_match_loss_kernel<<<NB, 64, 0, stream>>>(strokes, logits, tparams,
                                                  tlabels, acc);
  }
  detr_finalize_kernel<<<1, 1, 0, stream>>>(acc, (float*)d_out);
}

// Round 6
// 81.525 us; speedup vs baseline: 3.3252x; 1.0446x over previous
//
#include <hip/hip_runtime.h>
#include <math.h>
#include <stdint.h>

#define NB 128
#define NS 300   // pred slots (columns)
#define NG 100   // gt slots (max rows)
#define NP 10    // params per stroke
#define NSLOT 5  // ceil(NS/64)

// ws layout (all 8-aligned):
#define WS_ACC     0                         // 64 B
#define WS_ROWMIN  1024                      // NB*NG*8 = 102400
#define WS_ROWARG  103424                    // NB*NG*4 = 51200
#define WS_DCE     154624                    // NB*NS*2*8 = 614400
#define WS_BASECE  769024                    // NB*8 (pad to 1024)
#define WS_C       770048                    // NB*NG*NS*8 = 30720000
#define WS_NEEDED  (WS_C + (size_t)NB * NG * NS * 8)

#define GET_SLOT(arr, slot, out) do { switch (slot) { \
  case 0: out = arr[0]; break; case 1: out = arr[1]; break; \
  case 2: out = arr[2]; break; case 3: out = arr[3]; break; \
  default: out = arr[4]; break; } } while (0)
#define SET_SLOT(arr, slot, val) do { switch (slot) { \
  case 0: arr[0] = val; break; case 1: arr[1] = val; break; \
  case 2: arr[2] = val; break; case 3: arr[3] = val; break; \
  default: arr[4] = val; break; } } while (0)

__device__ __forceinline__ double wave_sum(double v) {
  #pragma unroll
  for (int off = 32; off > 0; off >>= 1) v += __shfl_xor(v, off);
  return v;
}

// ---- order-preserving f64 <-> u64 key ----
__device__ __forceinline__ uint64_t pack_key(double d) {
  const uint64_t b = (uint64_t)__double_as_longlong(d);
  return (b >> 63) ? ~b : (b | 0x8000000000000000ull);
}
__device__ __forceinline__ double unpack_key(uint64_t k) {
  const uint64_t b = (k >> 63) ? (k & 0x7fffffffffffffffull) : ~k;
  return __longlong_as_double((long long)b);
}

__device__ __forceinline__ double rl_f64(double v, int src) {
  const uint64_t b = (uint64_t)__double_as_longlong(v);
  const int lo = __builtin_amdgcn_readlane((int)(uint32_t)b, src);
  const int hi = __builtin_amdgcn_readlane((int)(uint32_t)(b >> 32), src);
  return __longlong_as_double((long long)(((uint64_t)(uint32_t)hi << 32) |
                                          (uint32_t)lo));
}

template <int CTRL>
__device__ __forceinline__ uint64_t dpp_u64_or_max(uint64_t x) {
  const int lo = (int)(uint32_t)x;
  const int hi = (int)(uint32_t)(x >> 32);
  const int lo2 = __builtin_amdgcn_update_dpp(-1, lo, CTRL, 0xF, 0xF, false);
  const int hi2 = __builtin_amdgcn_update_dpp(-1, hi, CTRL, 0xF, 0xF, false);
  return ((uint64_t)(uint32_t)hi2 << 32) | (uint32_t)lo2;
}

__device__ __forceinline__ void wave_argmin(uint64_t key, int bestj,
                                            double& minVal, int& jstar) {
  uint64_t k = key;
  { const uint64_t o = dpp_u64_or_max<0x111>(k); if (o < k) k = o; }
  { const uint64_t o = dpp_u64_or_max<0x112>(k); if (o < k) k = o; }
  { const uint64_t o = dpp_u64_or_max<0x114>(k); if (o < k) k = o; }
  { const uint64_t o = dpp_u64_or_max<0x118>(k); if (o < k) k = o; }
  { const uint64_t o = dpp_u64_or_max<0x142>(k); if (o < k) k = o; }
  { const uint64_t o = dpp_u64_or_max<0x143>(k); if (o < k) k = o; }
  const uint32_t mlo = (uint32_t)__builtin_amdgcn_readlane((int)(uint32_t)k, 63);
  const uint32_t mhi = (uint32_t)__builtin_amdgcn_readlane((int)(uint32_t)(k >> 32), 63);
  const uint64_t minkey = ((uint64_t)mhi << 32) | mlo;
  const unsigned long long winners = __ballot(key == minkey);
  const int src = __ffsll(winners) - 1;
  jstar = __builtin_amdgcn_readlane(bestj, src);
  minVal = unpack_key(minkey);
}

// ---------------------------------------------------------------------------
// Kernel B: precompute f64 cost matrix C[b][i][j] for valid rows i < nv.
// cb==0 blocks additionally emit the CE decomposition:
//   dce[b][s][c-1] = nll_c - 0.1*nll_0,  baseCE[b] = sum_s 0.1*nll_0.
// ---------------------------------------------------------------------------
__global__ __launch_bounds__(256) void detr_cost_kernel(
    const float* __restrict__ strokes,
    const float* __restrict__ logits,
    const float* __restrict__ tparams,
    const int*   __restrict__ tlabels,
    double*      __restrict__ C,
    double*      __restrict__ dce,
    double*      __restrict__ baseCE)
{
  __shared__ float  sS[NS * NP];
  __shared__ float  sP[NS * 3];
  __shared__ float  sVT[10 * NP];
  __shared__ int    sCls[10];
  __shared__ int    s_valid[NG];
  __shared__ int    s_vlab[NG];
  __shared__ int    s_nv;
  __shared__ double s_bp[4];

  const int b   = blockIdx.x;
  const int cb  = blockIdx.y;
  const int tid = threadIdx.x;

  for (int idx = tid; idx < NS * NP; idx += 256)
    sS[idx] = strokes[b * NS * NP + idx];

  for (int j = tid; j < NS; j += 256) {
    const float x0 = logits[(b * NS + j) * 3 + 0];
    const float x1 = logits[(b * NS + j) * 3 + 1];
    const float x2 = logits[(b * NS + j) * 3 + 2];
    const float m  = fmaxf(x0, fmaxf(x1, x2));
    const float e0 = expf(x0 - m), e1 = expf(x1 - m), e2 = expf(x2 - m);
    const float s  = e0 + e1 + e2;
    sP[j * 3 + 0] = e0 / s;
    sP[j * 3 + 1] = e1 / s;
    sP[j * 3 + 2] = e2 / s;
  }

  if (tid < 64) {
    const unsigned long long below = (1ull << tid) - 1ull;
    const int lb1 = tlabels[b * NG + tid];
    const bool in2 = tid < (NG - 64);
    const int lb2 = in2 ? tlabels[b * NG + 64 + tid] : 0;
    const unsigned long long m1 = __ballot(lb1 > 0);
    const unsigned long long m2 = __ballot(in2 && lb2 > 0);
    const int c1 = __popcll(m1);
    if (lb1 > 0) {
      const int p = __popcll(m1 & below);
      s_valid[p] = tid; s_vlab[p] = lb1;
    }
    if (in2 && lb2 > 0) {
      const int p = c1 + __popcll(m2 & below);
      s_valid[p] = 64 + tid; s_vlab[p] = lb2;
    }
    if (tid == 0) s_nv = c1 + __popcll(m2);
  }
  __syncthreads();

  // ---- CE decomposition (one block per batch: cb == 0) ----
  if (cb == 0) {
    double bsum = 0.0;
    for (int s = tid; s < NS; s += 256) {
      const double x0 = (double)logits[(b * NS + s) * 3 + 0];
      const double x1 = (double)logits[(b * NS + s) * 3 + 1];
      const double x2 = (double)logits[(b * NS + s) * 3 + 2];
      const double m   = fmax(x0, fmax(x1, x2));
      const double lse = log(exp(x0 - m) + exp(x1 - m) + exp(x2 - m));
      const double nll0 = -(x0 - m - lse);
      const double nll1 = -(x1 - m - lse);
      const double nll2 = -(x2 - m - lse);
      dce[((size_t)b * NS + s) * 2 + 0] = nll1 - 0.1 * nll0;
      dce[((size_t)b * NS + s) * 2 + 1] = nll2 - 0.1 * nll0;
      bsum += 0.1 * nll0;
    }
    bsum = wave_sum(bsum);
    if ((tid & 63) == 0) s_bp[tid >> 6] = bsum;
    __syncthreads();
    if (tid == 0) baseCE[b] = (s_bp[0] + s_bp[1]) + (s_bp[2] + s_bp[3]);
  }

  const int nv = s_nv;
  const int i0 = cb * 10;
  const int nrow = (nv - i0 < 10) ? (nv - i0) : 10;
  if (nrow <= 0) return;

  for (int idx = tid; idx < nrow * NP; idx += 256) {
    const int il = idx / NP, k = idx % NP;
    sVT[il * NP + k] = tparams[(b * NG + s_valid[i0 + il]) * NP + k];
  }
  if (tid < nrow) sCls[tid] = s_vlab[i0 + tid];
  __syncthreads();

  for (int e = tid; e < nrow * NS; e += 256) {
    const int il = e / NS, j = e - il * NS;
    const int cls = sCls[il];
    const double p = (double)sP[j * 3 + cls];
    double a[NP];
    #pragma unroll
    for (int k = 0; k < NP; ++k)
      a[k] = fabs((double)sS[j * NP + k] - (double)sVT[il * NP + k]);
    const double coord = ((a[0] + a[1]) + (a[2] + a[3])) +
                         ((a[4] + a[5]) + (a[6] + a[7]));
    const double c = -p + 5.0 * coord + 2.0 * (a[8] + a[9]) +
                     2.0 * (a[0] + a[1]);
    C[((size_t)b * NG + (i0 + il)) * NS + j] = c;
  }
}

// ---------------------------------------------------------------------------
// Kernel R: row minima, one wave per row, coalesced reads + DPP argmin.
// (Rows >= nv read unwritten ws garbage; results ignored downstream.)
// ---------------------------------------------------------------------------
__global__ __launch_bounds__(256) void detr_rowmin_kernel(
    const double* __restrict__ C,
    double*       __restrict__ rowmin,
    int*          __restrict__ rowarg)
{
  const int b    = blockIdx.x;
  const int i    = blockIdx.y * 4 + (threadIdx.x >> 6);
  const int lane = threadIdx.x & 63;
  const double* row = C + ((size_t)b * NG + i) * NS;
  const int vmask = (lane < NS - 4 * 64) ? 0x1F : 0x0F;

  double bestv = (double)INFINITY;
  int    bestj = 0x7fffffff;
  #pragma unroll
  for (int s = 0; s < NSLOT; ++s) {
    if ((vmask >> s) & 1) {
      const double c = row[lane + 64 * s];
      if (c < bestv) { bestv = c; bestj = lane + 64 * s; }
    }
  }
  double mv; int js;
  wave_argmin(pack_key(bestv), bestj, mv, js);
  if (lane == 0) { rowmin[b * NG + i] = mv; rowarg[b * NG + i] = js; }
}

// ---------------------------------------------------------------------------
// Kernel C: JV LAP — row-reduction warm start (precomputed) + greedy tight
// claims + SAP for conflict rows; fused regression + CE gathers.
// ---------------------------------------------------------------------------
__global__ __launch_bounds__(64) void detr_match_fast_kernel(
    const float*  __restrict__ strokes,
    const float*  __restrict__ tparams,
    const int*    __restrict__ tlabels,
    const double* __restrict__ C,
    const double* __restrict__ rowmin,
    const int*    __restrict__ rowarg,
    const double* __restrict__ dce,
    const double* __restrict__ baseCE,
    double*       __restrict__ acc)
{
  __shared__ int    s_valid[NG];
  __shared__ int    s_vlab[NG];
  __shared__ int    s_col4row[NG];
  __shared__ int    s_claimC[NS];
  __shared__ int    s_r4cL[NS];
  __shared__ double s_short[NS];

  const int b    = blockIdx.x;
  const int lane = threadIdx.x;

  for (int j = lane; j < NS; j += 64) {
    s_claimC[j] = 0x7fffffff; s_r4cL[j] = -1;
  }

  // stable compaction via ballots (ascending g = np.where order)
  const unsigned long long below = (1ull << lane) - 1ull;
  const int lb1 = tlabels[b * NG + lane];
  const bool in2 = lane < (NG - 64);
  const int lb2 = in2 ? tlabels[b * NG + 64 + lane] : 0;
  const unsigned long long m1 = __ballot(lb1 > 0);
  const unsigned long long m2 = __ballot(in2 && lb2 > 0);
  const int c1 = __popcll(m1);
  if (lb1 > 0) {
    const int p = __popcll(m1 & below);
    s_valid[p] = lane; s_vlab[p] = lb1;
  }
  if (in2 && lb2 > 0) {
    const int p = c1 + __popcll(m2 & below);
    s_valid[p] = 64 + lane; s_vlab[p] = lb2;
  }
  const int nv = c1 + __popcll(m2);

  for (int i = lane; i < nv; i += 64) s_col4row[i] = -1;
  __syncthreads();

  double wnll = 0.0;   // CE gather accumulator

  if (nv > 0) {
    const double* Cb = C + (size_t)b * NG * NS;
    const double INF = (double)INFINITY;
    const int vmask = (lane < NS - 4 * 64) ? 0x1F : 0x0F;

    // ---- precomputed row minima / argmins ----
    double rm0 = 0.0, rm1 = 0.0;
    int    ra0 = -1,  ra1 = -1;
    if (lane < nv) {
      rm0 = rowmin[b * NG + lane];
      ra0 = rowarg[b * NG + lane];
    }
    if (lane + 64 < nv) {
      rm1 = rowmin[b * NG + lane + 64];
      ra1 = rowarg[b * NG + lane + 64];
    }

    // ---- greedy tight claims: lowest row index wins a contested column ----
    if (lane < nv)      atomicMin(&s_claimC[ra0], lane);
    if (lane + 64 < nv) atomicMin(&s_claimC[ra1], lane + 64);
    __syncthreads();
    if (lane < nv && s_claimC[ra0] == lane) {
      s_r4cL[ra0] = lane; s_col4row[lane] = ra0;
    }
    if (lane + 64 < nv && s_claimC[ra1] == lane + 64) {
      s_r4cL[ra1] = lane + 64; s_col4row[lane + 64] = ra1;
    }
    __syncthreads();

    // register column state
    int r4c[NSLOT];
    #pragma unroll
    for (int s = 0; s < NSLOT; ++s)
      r4c[s] = ((vmask >> s) & 1) ? s_r4cL[lane + 64 * s] : -1;
    double vv[NSLOT];
    #pragma unroll
    for (int s = 0; s < NSLOT; ++s) vv[s] = 0.0;

    // u duals in registers (warm-started to row minima)
    double u0 = rm0, u1 = rm1;

    // free rows = claim losers
    unsigned long long f0 = __ballot(lane < nv && s_col4row[lane] < 0);
    unsigned long long f1 = __ballot(lane + 64 < nv && s_col4row[lane + 64] < 0);

    while (f0 | f1) {
      int cur;
      if (f0) { cur = __ffsll(f0) - 1; f0 &= f0 - 1; }
      else    { cur = 64 + __ffsll(f1) - 1; f1 &= f1 - 1; }

      double sh[NSLOT];
      int    pa[NSLOT];
      #pragma unroll
      for (int s = 0; s < NSLOT; ++s) { sh[s] = INF; pa[s] = -1; }
      int scm = 0;
      unsigned long long srm0 = 0ull, srm1 = 0ull;
      double minVal = 0.0;
      int i = cur;
      int sink = -1;

      while (sink == -1) {
        if (i < 64) srm0 |= (1ull << i); else srm1 |= (1ull << (i - 64));
        const double ucur = (i < 64) ? rl_f64(u0, i) : rl_f64(u1, i - 64);
        const double base = minVal - ucur;
        const double* Gr = Cb + (size_t)i * NS;

        double bestv = INF;
        int    bestj = 0x7fffffff;
        #pragma unroll
        for (int s = 0; s < NSLOT; ++s) {
          if ((vmask >> s) & 1) {
            const double c = Gr[lane + 64 * s];
            if (!((scm >> s) & 1)) {
              const double d = base + c - vv[s];
              if (d < sh[s]) { sh[s] = d; pa[s] = i; }
              if (sh[s] < bestv) { bestv = sh[s]; bestj = lane + 64 * s; }
            }
          }
        }

        double mv; int jstar;
        wave_argmin(pack_key(bestv), bestj, mv, jstar);
        minVal = mv;
        const int slot = jstar >> 6;
        const int src  = jstar & 63;
        if (lane == src) scm |= (1 << slot);

        int t;
        GET_SLOT(r4c, slot, t);
        const int rc = __builtin_amdgcn_readlane(t, src);
        if (rc < 0) sink = jstar; else i = rc;
      }

      // expose shortest for dual updates
      #pragma unroll
      for (int s = 0; s < NSLOT; ++s)
        if ((vmask >> s) & 1) s_short[lane + 64 * s] = sh[s];
      __syncthreads();

      if (((srm0 >> lane) & 1ull) && lane != cur)
        u0 += minVal - s_short[s_col4row[lane]];
      const int r2 = lane + 64;
      if (((srm1 >> lane) & 1ull) && r2 != cur)
        u1 += minVal - s_short[s_col4row[r2]];
      if (lane == cur) u0 += minVal;
      if (r2 == cur)   u1 += minVal;
      #pragma unroll
      for (int s = 0; s < NSLOT; ++s)
        if ((scm >> s) & 1) vv[s] -= minVal - sh[s];
      __syncthreads();

      // augmenting-path flip
      int j = sink;
      while (true) {
        const int slot = j >> 6, src = j & 63;
        int t;
        GET_SLOT(pa, slot, t);
        const int i2 = __builtin_amdgcn_readlane(t, src);
        if (lane == src) SET_SLOT(r4c, slot, i2);
        const int nxt = s_col4row[i2];
        if (lane == 0) s_col4row[i2] = j;
        if (i2 == cur) break;
        j = nxt;
      }
      __syncthreads();
    }

    // matched regression partials + CE delta gathers
    double l1 = 0.0, sl1 = 0.0, wid = 0.0;
    for (int i = lane; i < nv; i += 64) {
      const int r = s_col4row[i];
      const int c = s_vlab[i];
      wnll += dce[((size_t)b * NS + r) * 2 + (c - 1)];
      const float* ps = strokes + ((size_t)b * NS + r) * NP;
      const float* tp = tparams + ((size_t)b * NG + s_valid[i]) * NP;
      #pragma unroll
      for (int k = 0; k < 8; ++k) {
        const float d  = ps[k] - tp[k];
        const float ad = fabsf(d);
        l1 += (double)ad;
        const float sm = (ad < 0.1f) ? (0.5f * ad * ad / 0.1f) : (ad - 0.05f);
        sl1 += (double)sm;
      }
      const float d8 = fabsf(ps[8] - tp[8]);
      const float d9 = fabsf(ps[9] - tp[9]);
      wid += (double)d8 + (double)d9;
    }
    l1 = wave_sum(l1); sl1 = wave_sum(sl1); wid = wave_sum(wid);
    if (lane == 0) {
      atomicAdd(&acc[2], l1);
      atomicAdd(&acc[3], sl1);
      atomicAdd(&acc[4], wid);
      atomicAdd(&acc[5], (double)nv);
    }
  }

  // CE totals (runs for nv == 0 too: base + wsum contribution)
  wnll = wave_sum(wnll);
  if (lane == 0) {
    atomicAdd(&acc[0], wnll + baseCE[b]);
    atomicAdd(&acc[1], 30.0 + 0.9 * (double)nv);
  }
}

// ---------------------------------------------------------------------------
// Fallback (ws too small): round-0 monolithic kernel (proven, absmax 0.0).
// ---------------------------------------------------------------------------
__global__ __launch_bounds__(64) void detr_match_loss_kernel(
    const float* __restrict__ strokes,
    const float* __restrict__ logits,
    const float* __restrict__ tparams,
    const int*   __restrict__ tlabels,
    double*      __restrict__ acc)
{
  __shared__ float  s_strokes[NS * NP];
  __shared__ float  s_probs[NS * 3];
  __shared__ float  s_vt[NG * NP];
  __shared__ int    s_valid[NG];
  __shared__ int    s_vlab[NG];
  __shared__ double s_u[NG];
  __shared__ int    s_col4row[NG];
  __shared__ int    s_SRb[NG];
  __shared__ double s_shortest[NS];
  __shared__ double s_v[NS];
  __shared__ int    s_path[NS];
  __shared__ int    s_SC[NS];
  __shared__ int    s_row4col[NS];
  __shared__ int    s_tc[NS];
  __shared__ int    s_nv;

  const int b    = blockIdx.x;
  const int lane = threadIdx.x;

  for (int idx = lane; idx < NS * NP; idx += 64)
    s_strokes[idx] = strokes[b * NS * NP + idx];

  for (int j = lane; j < NS; j += 64) {
    const float x0 = logits[(b * NS + j) * 3 + 0];
    const float x1 = logits[(b * NS + j) * 3 + 1];
    const float x2 = logits[(b * NS + j) * 3 + 2];
    const float m  = fmaxf(x0, fmaxf(x1, x2));
    const float e0 = expf(x0 - m), e1 = expf(x1 - m), e2 = expf(x2 - m);
    const float s  = e0 + e1 + e2;
    s_probs[j * 3 + 0] = e0 / s;
    s_probs[j * 3 + 1] = e1 / s;
    s_probs[j * 3 + 2] = e2 / s;
    s_tc[j]      = 0;
    s_row4col[j] = -1;
    s_v[j]       = 0.0;
  }

  if (lane == 0) {
    int nv = 0;
    for (int g = 0; g < NG; ++g) {
      const int lb = tlabels[b * NG + g];
      if (lb > 0) { s_valid[nv] = g; s_vlab[nv] = lb; ++nv; }
    }
    s_nv = nv;
  }
  __syncthreads();
  const int nv = s_nv;

  for (int idx = lane; idx < nv * NP; idx += 64) {
    const int i = idx / NP, k = idx % NP;
    s_vt[idx] = tparams[(b * NG + s_valid[i]) * NP + k];
  }
  for (int i = lane; i < nv; i += 64) { s_u[i] = 0.0; s_col4row[i] = -1; }
  __syncthreads();

  if (nv > 0) {
    for (int cur = 0; cur < nv; ++cur) {
      for (int j = lane; j < NS; j += 64) {
        s_shortest[j] = 1e300;
        s_path[j]     = -1;
        s_SC[j]       = 0;
      }
      for (int r = lane; r < nv; r += 64) s_SRb[r] = 0;
      __syncthreads();

      double minVal = 0.0;
      int i = cur;
      int sink = -1;

      while (sink == -1) {
        if (lane == 0) s_SRb[i] = 1;
        const double ui  = s_u[i];
        const int    cls = s_vlab[i];
        double vtr[NP];
        #pragma unroll
        for (int k = 0; k < NP; ++k) vtr[k] = (double)s_vt[i * NP + k];
        const double base = minVal - ui;

        double bestv = 1e300;
        int    bestj = 0x7fffffff;

        for (int j = lane; j < NS; j += 64) {
          if (!s_SC[j]) {
            const double p = (double)s_probs[j * 3 + cls];
            double a[NP];
            #pragma unroll
            for (int k = 0; k < NP; ++k)
              a[k] = fabs((double)s_strokes[j * NP + k] - vtr[k]);
            const double coord = ((a[0] + a[1]) + (a[2] + a[3])) +
                                 ((a[4] + a[5]) + (a[6] + a[7]));
            const double c = -p + 5.0 * coord + 2.0 * (a[8] + a[9]) +
                             2.0 * (a[0] + a[1]);
            const double d = base + c - s_v[j];
            if (d < s_shortest[j]) { s_shortest[j] = d; s_path[j] = i; }
            const double sv = s_shortest[j];
            if (sv < bestv) { bestv = sv; bestj = j; }
          }
        }

        #pragma unroll
        for (int off = 32; off > 0; off >>= 1) {
          const double ov = __shfl_xor(bestv, off);
          const int    oj = __shfl_xor(bestj, off);
          if (ov < bestv || (ov == bestv && oj < bestj)) { bestv = ov; bestj = oj; }
        }
        minVal = bestv;
        const int jstar = bestj;
        if (lane == 0) s_SC[jstar] = 1;
        __syncthreads();
        const int rc = s_row4col[jstar];
        if (rc < 0) sink = jstar; else i = rc;
      }

      for (int r = lane; r < nv; r += 64)
        if (s_SRb[r] && r != cur)
          s_u[r] += minVal - s_shortest[s_col4row[r]];
      if (lane == 0) s_u[cur] += minVal;
      for (int j = lane; j < NS; j += 64)
        if (s_SC[j]) s_v[j] -= minVal - s_shortest[j];
      __syncthreads();

      if (lane == 0) {
        int j = sink;
        while (true) {
          const int i2 = s_path[j];
          s_row4col[j] = i2;
          const int nxt = s_col4row[i2];
          s_col4row[i2] = j;
          if (i2 == cur) break;
          j = nxt;
        }
      }
      __syncthreads();
    }

    double l1 = 0.0, sl1 = 0.0, wid = 0.0;
    for (int i = lane; i < nv; i += 64) {
      const int r = s_col4row[i];
      s_tc[r] = s_vlab[i];
      #pragma unroll
      for (int k = 0; k < 8; ++k) {
        const float d  = s_strokes[r * NP + k] - s_vt[i * NP + k];
        const float ad = fabsf(d);
        l1 += (double)ad;
        const float s = (ad < 0.1f) ? (0.5f * ad * ad / 0.1f) : (ad - 0.05f);
        sl1 += (double)s;
      }
      const float d8 = fabsf(s_strokes[r * NP + 8] - s_vt[i * NP + 8]);
      const float d9 = fabsf(s_strokes[r * NP + 9] - s_vt[i * NP + 9]);
      wid += (double)d8 + (double)d9;
    }
    l1 = wave_sum(l1); sl1 = wave_sum(sl1); wid = wave_sum(wid);
    if (lane == 0) {
      atomicAdd(&acc[2], l1);
      atomicAdd(&acc[3], sl1);
      atomicAdd(&acc[4], wid);
      atomicAdd(&acc[5], (double)nv);
    }
  }
  __syncthreads();

  double wnll = 0.0, wsum = 0.0;
  for (int s = lane; s < NS; s += 64) {
    const int tc = s_tc[s];
    const double x0 = (double)logits[(b * NS + s) * 3 + 0];
    const double x1 = (double)logits[(b * NS + s) * 3 + 1];
    const double x2 = (double)logits[(b * NS + s) * 3 + 2];
    const double m   = fmax(x0, fmax(x1, x2));
    const double lse = log(exp(x0 - m) + exp(x1 - m) + exp(x2 - m));
    const double xt  = (tc == 0) ? x0 : ((tc == 1) ? x1 : x2);
    const double nll = -(xt - m - lse);
    const double w   = (tc == 0) ? 0.1 : 1.0;
    wnll += w * nll;
    wsum += w;
  }
  wnll = wave_sum(wnll); wsum = wave_sum(wsum);
  if (lane == 0) {
    atomicAdd(&acc[0], wnll);
    atomicAdd(&acc[1], wsum);
  }
}

__global__ void detr_finalize_kernel(const double* __restrict__ acc,
                                     float* __restrict__ out) {
  const double loss_ce = acc[0] / acc[1];
  const double denom   = fmax(acc[5], 1.0);
  const double loss = 1.0 * loss_ce
                    + 5.0 * (acc[2] + acc[3]) / denom
                    + 2.0 * acc[4] / denom;
  out[0] = (float)loss;
}

extern "C" void kernel_launch(void* const* d_in, const int* in_sizes, int n_in,
                              void* d_out, int out_size, void* d_ws, size_t ws_size,
                              hipStream_t stream) {
  const float* strokes = (const float*)d_in[0];
  const float* logits  = (const float*)d_in[1];
  const float* tparams = (const float*)d_in[2];
  const int*   tlabels = (const int*)d_in[3];
  char* ws = (char*)d_ws;
  double* acc = (double*)(ws + WS_ACC);

  hipMemsetAsync(d_ws, 0, 64, stream);

  if (ws_size >= WS_NEEDED) {
    double* rowmin = (double*)(ws + WS_ROWMIN);
    int*    rowarg = (int*)(ws + WS_ROWARG);
    double* dce    = (double*)(ws + WS_DCE);
    double* baseCE = (double*)(ws + WS_BASECE);
    double* C      = (double*)(ws + WS_C);

    detr_cost_kernel<<<dim3(NB, 10), 256, 0, stream>>>(
        strokes, logits, tparams, tlabels, C, dce, baseCE);
    detr_rowmin_kernel<<<dim3(NB, NG / 4), 256, 0, stream>>>(C, rowmin, rowarg);
    detr_match_fast_kernel<<<NB, 64, 0, stream>>>(
        strokes, tparams, tlabels, C, rowmin, rowarg, dce, baseCE, acc);
  } else {
    detr_match_loss_kernel<<<NB, 64, 0, stream>>>(strokes, logits, tparams,
                                                  tlabels, acc);
  }
  detr_finalize_kernel<<<1, 1, 0, stream>>>(acc, (float*)d_out);
}